// Round 1
// baseline (7596.365 us; speedup 1.0000x reference)
//
#include <hip/hip_runtime.h>
#include <cmath>

#define Dm   512
#define Hn   8
#define Ln   6
#define DFFm 2048
#define Vm   32000
#define Bn   2
#define Sn   1024
#define DHm  64
#define Mrows (Bn*Sn)   // 2048

// ---------------------------------------------------------------------------
// Generic tiled fp32 GEMM: C[M,N] = A[M,K] @ B[K,N] (+bias) (+relu)
// Batched over grid.z with per-b / per-h pointer offsets (z -> b=z/nh, h=z%nh).
// Requires M%64==0, N%64==0, K%16==0 (true for every shape used here).
// ---------------------------------------------------------------------------
template<bool BIAS, bool RELU>
__global__ __launch_bounds__(256) void gemm_nn(
    const float* __restrict__ A, const float* __restrict__ B, float* __restrict__ C,
    const float* __restrict__ bias, int M, int N, int K, int lda, int ldb, int ldc,
    long A_sb, long A_sh, long B_sb, long B_sh, long C_sb, long C_sh, int nh)
{
    int z = blockIdx.z;
    int b = z / nh, h = z % nh;
    A += (long)b * A_sb + (long)h * A_sh;
    B += (long)b * B_sb + (long)h * B_sh;
    C += (long)b * C_sb + (long)h * C_sh;

    __shared__ float As[16][65];   // transposed: As[k][m]
    __shared__ float Bs[16][68];   // Bs[k][n], padded stride 68 (16B-aligned rows)

    const int tid = threadIdx.y * 16 + threadIdx.x;
    const int m0 = blockIdx.y * 64, n0 = blockIdx.x * 64;

    float acc[4][4] = {};

    for (int k0 = 0; k0 < K; k0 += 16) {
        // A tile 64x16 -> transposed into As[k][m]
        {
            int row = tid >> 2;            // 0..63 (m)
            int q   = (tid & 3) * 4;       // 0,4,8,12 (k)
            const float4 av = *(const float4*)(A + (long)(m0 + row) * lda + k0 + q);
            As[q + 0][row] = av.x; As[q + 1][row] = av.y;
            As[q + 2][row] = av.z; As[q + 3][row] = av.w;
        }
        // B tile 16x64
        {
            int row = tid >> 4;            // 0..15 (k)
            int q   = (tid & 15) * 4;      // 0..60 (n)
            *(float4*)(&Bs[row][q]) = *(const float4*)(B + (long)(k0 + row) * ldb + n0 + q);
        }
        __syncthreads();
        #pragma unroll
        for (int kk = 0; kk < 16; ++kk) {
            float a[4], bb[4];
            #pragma unroll
            for (int i = 0; i < 4; ++i) a[i]  = As[kk][threadIdx.y * 4 + i];
            #pragma unroll
            for (int j = 0; j < 4; ++j) bb[j] = Bs[kk][threadIdx.x * 4 + j];
            #pragma unroll
            for (int i = 0; i < 4; ++i)
                #pragma unroll
                for (int j = 0; j < 4; ++j)
                    acc[i][j] += a[i] * bb[j];
        }
        __syncthreads();
    }

    #pragma unroll
    for (int i = 0; i < 4; ++i) {
        int m = m0 + threadIdx.y * 4 + i;
        #pragma unroll
        for (int j = 0; j < 4; ++j) {
            int n = n0 + threadIdx.x * 4 + j;
            float v = acc[i][j];
            if (BIAS) v += bias[n];
            if (RELU) v = fmaxf(v, 0.f);
            C[(long)m * ldc + n] = v;
        }
    }
}

// ---------------------------------------------------------------------------
// QK^T: S[z][q][k] = scale * dot64(Q[q,:], K[k,:])   (K dim = DH = 64, one pass)
// ---------------------------------------------------------------------------
__global__ __launch_bounds__(256) void qk_nt(
    const float* __restrict__ Q, const float* __restrict__ Kp, float* __restrict__ S,
    int ldq, int ldk, long Q_sb, long Q_sh, long K_sb, long K_sh, int nh, float scale)
{
    int z = blockIdx.z;
    int b = z / nh, h = z % nh;
    Q  += (long)b * Q_sb + (long)h * Q_sh;
    Kp += (long)b * K_sb + (long)h * K_sh;
    S  += (long)z * Sn * Sn;

    __shared__ float Qs[64][65];   // Qs[k][m]
    __shared__ float Ks[64][65];   // Ks[k][n]

    const int tid = threadIdx.y * 16 + threadIdx.x;
    const int m0 = blockIdx.y * 64, n0 = blockIdx.x * 64;

    #pragma unroll
    for (int r = 0; r < 4; ++r) {
        int idx  = tid + r * 256;      // 0..1023 float4 slots
        int row  = idx >> 4;           // 0..63
        int col4 = (idx & 15) * 4;     // 0..60
        float4 qv = *(const float4*)(Q  + (long)(m0 + row) * ldq + col4);
        float4 kv = *(const float4*)(Kp + (long)(n0 + row) * ldk + col4);
        Qs[col4 + 0][row] = qv.x; Qs[col4 + 1][row] = qv.y;
        Qs[col4 + 2][row] = qv.z; Qs[col4 + 3][row] = qv.w;
        Ks[col4 + 0][row] = kv.x; Ks[col4 + 1][row] = kv.y;
        Ks[col4 + 2][row] = kv.z; Ks[col4 + 3][row] = kv.w;
    }
    __syncthreads();

    float acc[4][4] = {};
    #pragma unroll 8
    for (int kk = 0; kk < 64; ++kk) {
        float a[4], bb[4];
        #pragma unroll
        for (int i = 0; i < 4; ++i) a[i]  = Qs[kk][threadIdx.y * 4 + i];
        #pragma unroll
        for (int j = 0; j < 4; ++j) bb[j] = Ks[kk][threadIdx.x * 4 + j];
        #pragma unroll
        for (int i = 0; i < 4; ++i)
            #pragma unroll
            for (int j = 0; j < 4; ++j)
                acc[i][j] += a[i] * bb[j];
    }

    #pragma unroll
    for (int i = 0; i < 4; ++i) {
        int m = m0 + threadIdx.y * 4 + i;
        #pragma unroll
        for (int j = 0; j < 4; ++j) {
            int n = n0 + threadIdx.x * 4 + j;
            S[(long)m * Sn + n] = acc[i][j] * scale;
        }
    }
}

// ---------------------------------------------------------------------------
// Row softmax with masking. mode 0: pad mask (tok[k]==0 blocked); mode 1: causal.
// One block (256 thr) per row of Sn=1024. In-place.
// ---------------------------------------------------------------------------
__global__ __launch_bounds__(256) void softmax_mask(
    float* __restrict__ sc, const int* __restrict__ tok, int mode, int nh)
{
    long row = blockIdx.x;                 // (b*Hn + h)*Sn + q
    int q = (int)(row % Sn);
    int b = (int)(row / ((long)nh * Sn));
    float* p = sc + row * Sn;
    const int* tb = tok ? tok + (long)b * Sn : nullptr;

    const int t = threadIdx.x;
    float v[4];
    float mx = -1e30f;
    #pragma unroll
    for (int r = 0; r < 4; ++r) {
        int k = t + r * 256;
        float val = p[k];
        bool m = (mode == 0) ? (tb[k] == 0) : (k > q);
        if (m) val = -1e9f;
        v[r] = val;
        mx = fmaxf(mx, val);
    }
    __shared__ float redm[4], reds[4];
    for (int off = 32; off; off >>= 1) mx = fmaxf(mx, __shfl_down(mx, off));
    int lane = t & 63, w = t >> 6;
    if (lane == 0) redm[w] = mx;
    __syncthreads();
    mx = fmaxf(fmaxf(redm[0], redm[1]), fmaxf(redm[2], redm[3]));

    float sum = 0.f;
    #pragma unroll
    for (int r = 0; r < 4; ++r) { v[r] = expf(v[r] - mx); sum += v[r]; }
    for (int off = 32; off; off >>= 1) sum += __shfl_down(sum, off);
    if (lane == 0) reds[w] = sum;
    __syncthreads();
    sum = reds[0] + reds[1] + reds[2] + reds[3];

    float inv = 1.f / sum;
    #pragma unroll
    for (int r = 0; r < 4; ++r) p[t + r * 256] = v[r] * inv;
}

// ---------------------------------------------------------------------------
// y = layernorm(x + o) * s + b, in-place into x. One block per row (D=512).
// ---------------------------------------------------------------------------
__global__ __launch_bounds__(256) void add_ln(
    float* __restrict__ x, const float* __restrict__ o,
    const float* __restrict__ s, const float* __restrict__ bb)
{
    long row = blockIdx.x;
    const int t = threadIdx.x;
    float* xr = x + row * Dm;
    const float* orr = o + row * Dm;
    float v0 = xr[t] + orr[t];
    float v1 = xr[t + 256] + orr[t + 256];

    float sum = v0 + v1, ssq = v0 * v0 + v1 * v1;
    __shared__ float red[8];
    for (int off = 32; off; off >>= 1) {
        sum += __shfl_down(sum, off);
        ssq += __shfl_down(ssq, off);
    }
    int lane = t & 63, w = t >> 6;
    if (lane == 0) { red[w] = sum; red[4 + w] = ssq; }
    __syncthreads();
    sum = red[0] + red[1] + red[2] + red[3];
    ssq = red[4] + red[5] + red[6] + red[7];

    float mean = sum * (1.f / Dm);
    float var  = ssq * (1.f / Dm) - mean * mean;
    float r = rsqrtf(var + 1e-5f);
    xr[t]       = (v0 - mean) * r * s[t]       + bb[t];
    xr[t + 256] = (v1 - mean) * r * s[t + 256] + bb[t + 256];
}

// ---------------------------------------------------------------------------
// x[b,s,:] = emb[tok[b,s],:] * sqrt(D) + posenc(s,:)
// ---------------------------------------------------------------------------
__global__ __launch_bounds__(256) void embed_pe(
    const int* __restrict__ tok, const float* __restrict__ emb, float* __restrict__ out)
{
    int bs = blockIdx.x;
    int s = bs % Sn;
    int t = threadIdx.x;
    int token = tok[bs];
    #pragma unroll
    for (int r = 0; r < 2; ++r) {
        int d = t + r * 256;
        int i = d & ~1;
        float ang = (float)s * powf(10000.0f, -(float)i / (float)Dm);
        float pe = (d & 1) ? cosf(ang) : sinf(ang);
        out[(long)bs * Dm + d] = emb[(long)token * Dm + d] * 22.627416997969522f + pe;
    }
}

// ---------------------------------------------------------------------------
extern "C" void kernel_launch(void* const* d_in, const int* in_sizes, int n_in,
                              void* d_out, int out_size, void* d_ws, size_t ws_size,
                              hipStream_t stream)
{
    const int*   batch_src = (const int*)d_in[0];
    const int*   trg       = (const int*)d_in[1];
    const float* src_emb   = (const float*)d_in[2];
    const float* trg_emb   = (const float*)d_in[3];
    const float* fc_w      = (const float*)d_in[4];
    const float* fc_b      = (const float*)d_in[5];
    const float* enc_wqkv  = (const float*)d_in[6];
    const float* enc_wo    = (const float*)d_in[7];
    const float* enc_ln1s  = (const float*)d_in[8];
    const float* enc_ln1b  = (const float*)d_in[9];
    const float* enc_w1    = (const float*)d_in[10];
    const float* enc_b1    = (const float*)d_in[11];
    const float* enc_w2    = (const float*)d_in[12];
    const float* enc_b2    = (const float*)d_in[13];
    const float* enc_ln2s  = (const float*)d_in[14];
    const float* enc_ln2b  = (const float*)d_in[15];
    const float* dec_wqkv  = (const float*)d_in[16];
    const float* dec_wo    = (const float*)d_in[17];
    const float* dec_ln1s  = (const float*)d_in[18];
    const float* dec_ln1b  = (const float*)d_in[19];
    const float* dec_wq    = (const float*)d_in[20];
    const float* dec_wkv   = (const float*)d_in[21];
    const float* dec_woc   = (const float*)d_in[22];
    const float* dec_ln2s  = (const float*)d_in[23];
    const float* dec_ln2b  = (const float*)d_in[24];
    const float* dec_w1    = (const float*)d_in[25];
    const float* dec_b1    = (const float*)d_in[26];
    const float* dec_w2    = (const float*)d_in[27];
    const float* dec_b2    = (const float*)d_in[28];
    const float* dec_ln3s  = (const float*)d_in[29];
    const float* dec_ln3b  = (const float*)d_in[30];

    float* ws = (float*)d_ws;
    float* X   = ws;               // encoder activations -> enc_out   [2048,512]
    float* Y   = X   + 1048576;    // decoder activations              [2048,512]
    float* QKV = Y   + 1048576;    // qkv proj                         [2048,1536]
    float* SC  = QKV + 3145728;    // scores                           [16,1024,1024]
    float* AO  = SC  + 16777216;   // attention out (merged heads)     [2048,512]
    float* O   = AO  + 1048576;    // projection out                   [2048,512]
    float* FH  = O   + 1048576;    // ff hidden                        [2048,2048]
    float* QC  = FH  + 4194304;    // cross q                          [2048,512]
    float* KV  = QC  + 1048576;    // cross kv                         [2048,1024]
    (void)ws_size; (void)in_sizes; (void)n_in; (void)out_size;

    const dim3 t16(16, 16);
    const long SBH = (long)Sn * Sn;            // per-(b,h) score stride
    const long Q3  = (long)Sn * 3 * Dm;        // qkv per-batch stride
    const long QD  = (long)Sn * Dm;
    const long KV2 = (long)Sn * 2 * Dm;

    embed_pe<<<Mrows, 256, 0, stream>>>(batch_src, src_emb, X);
    embed_pe<<<Mrows, 256, 0, stream>>>(trg,       trg_emb, Y);

    // ------------------------------ encoder ------------------------------
    for (int l = 0; l < Ln; ++l) {
        gemm_nn<false,false><<<dim3(24, 32, 1), t16, 0, stream>>>(
            X, enc_wqkv + (long)l*Dm*3*Dm, QKV, nullptr,
            Mrows, 3*Dm, Dm, Dm, 3*Dm, 3*Dm, 0,0,0,0,0,0, 1);
        qk_nt<<<dim3(16, 16, Bn*Hn), t16, 0, stream>>>(
            QKV, QKV + Dm, SC, 3*Dm, 3*Dm, Q3, DHm, Q3, DHm, Hn, 0.125f);
        softmax_mask<<<Bn*Hn*Sn, 256, 0, stream>>>(SC, batch_src, 0, Hn);
        gemm_nn<false,false><<<dim3(1, 16, Bn*Hn), t16, 0, stream>>>(
            SC, QKV + 2*Dm, AO, nullptr,
            Sn, DHm, Sn, Sn, 3*Dm, Dm, (long)Hn*SBH, SBH, Q3, DHm, QD, DHm, Hn);
        gemm_nn<false,false><<<dim3(8, 32, 1), t16, 0, stream>>>(
            AO, enc_wo + (long)l*Dm*Dm, O, nullptr,
            Mrows, Dm, Dm, Dm, Dm, Dm, 0,0,0,0,0,0, 1);
        add_ln<<<Mrows, 256, 0, stream>>>(X, O, enc_ln1s + l*Dm, enc_ln1b + l*Dm);
        gemm_nn<true,true><<<dim3(32, 32, 1), t16, 0, stream>>>(
            X, enc_w1 + (long)l*Dm*DFFm, FH, enc_b1 + l*DFFm,
            Mrows, DFFm, Dm, Dm, DFFm, DFFm, 0,0,0,0,0,0, 1);
        gemm_nn<true,false><<<dim3(8, 32, 1), t16, 0, stream>>>(
            FH, enc_w2 + (long)l*DFFm*Dm, O, enc_b2 + l*Dm,
            Mrows, Dm, DFFm, DFFm, Dm, Dm, 0,0,0,0,0,0, 1);
        add_ln<<<Mrows, 256, 0, stream>>>(X, O, enc_ln2s + l*Dm, enc_ln2b + l*Dm);
    }

    // ------------------------------ decoder ------------------------------
    for (int l = 0; l < Ln; ++l) {
        // self-attention (causal)
        gemm_nn<false,false><<<dim3(24, 32, 1), t16, 0, stream>>>(
            Y, dec_wqkv + (long)l*Dm*3*Dm, QKV, nullptr,
            Mrows, 3*Dm, Dm, Dm, 3*Dm, 3*Dm, 0,0,0,0,0,0, 1);
        qk_nt<<<dim3(16, 16, Bn*Hn), t16, 0, stream>>>(
            QKV, QKV + Dm, SC, 3*Dm, 3*Dm, Q3, DHm, Q3, DHm, Hn, 0.125f);
        softmax_mask<<<Bn*Hn*Sn, 256, 0, stream>>>(SC, nullptr, 1, Hn);
        gemm_nn<false,false><<<dim3(1, 16, Bn*Hn), t16, 0, stream>>>(
            SC, QKV + 2*Dm, AO, nullptr,
            Sn, DHm, Sn, Sn, 3*Dm, Dm, (long)Hn*SBH, SBH, Q3, DHm, QD, DHm, Hn);
        gemm_nn<false,false><<<dim3(8, 32, 1), t16, 0, stream>>>(
            AO, dec_wo + (long)l*Dm*Dm, O, nullptr,
            Mrows, Dm, Dm, Dm, Dm, Dm, 0,0,0,0,0,0, 1);
        add_ln<<<Mrows, 256, 0, stream>>>(Y, O, dec_ln1s + l*Dm, dec_ln1b + l*Dm);

        // cross-attention (pad mask)
        gemm_nn<false,false><<<dim3(8, 32, 1), t16, 0, stream>>>(
            Y, dec_wq + (long)l*Dm*Dm, QC, nullptr,
            Mrows, Dm, Dm, Dm, Dm, Dm, 0,0,0,0,0,0, 1);
        gemm_nn<false,false><<<dim3(16, 32, 1), t16, 0, stream>>>(
            X, dec_wkv + (long)l*Dm*2*Dm, KV, nullptr,
            Mrows, 2*Dm, Dm, Dm, 2*Dm, 2*Dm, 0,0,0,0,0,0, 1);
        qk_nt<<<dim3(16, 16, Bn*Hn), t16, 0, stream>>>(
            QC, KV, SC, Dm, 2*Dm, QD, DHm, KV2, DHm, Hn, 0.125f);
        softmax_mask<<<Bn*Hn*Sn, 256, 0, stream>>>(SC, batch_src, 0, Hn);
        gemm_nn<false,false><<<dim3(1, 16, Bn*Hn), t16, 0, stream>>>(
            SC, KV + Dm, AO, nullptr,
            Sn, DHm, Sn, Sn, 2*Dm, Dm, (long)Hn*SBH, SBH, KV2, DHm, QD, DHm, Hn);
        gemm_nn<false,false><<<dim3(8, 32, 1), t16, 0, stream>>>(
            AO, dec_woc + (long)l*Dm*Dm, O, nullptr,
            Mrows, Dm, Dm, Dm, Dm, Dm, 0,0,0,0,0,0, 1);
        add_ln<<<Mrows, 256, 0, stream>>>(Y, O, dec_ln2s + l*Dm, dec_ln2b + l*Dm);

        // feed-forward
        gemm_nn<true,true><<<dim3(32, 32, 1), t16, 0, stream>>>(
            Y, dec_w1 + (long)l*Dm*DFFm, FH, dec_b1 + l*DFFm,
            Mrows, DFFm, Dm, Dm, DFFm, DFFm, 0,0,0,0,0,0, 1);
        gemm_nn<true,false><<<dim3(8, 32, 1), t16, 0, stream>>>(
            FH, dec_w2 + (long)l*DFFm*Dm, O, dec_b2 + l*Dm,
            Mrows, Dm, DFFm, DFFm, Dm, Dm, 0,0,0,0,0,0, 1);
        add_ln<<<Mrows, 256, 0, stream>>>(Y, O, dec_ln3s + l*Dm, dec_ln3b + l*Dm);
    }

    // final projection to vocab
    gemm_nn<true,false><<<dim3(Vm/64, 32, 1), t16, 0, stream>>>(
        Y, fc_w, (float*)d_out, fc_b,
        Mrows, Vm, Dm, Dm, Vm, Vm, 0,0,0,0,0,0, 1);
}

// Round 3
// 2390.061 us; speedup vs baseline: 3.1783x; 3.1783x over previous
//
#include <hip/hip_runtime.h>
#include <cmath>

#define Dm   512
#define Hn   8
#define Ln   6
#define DFFm 2048
#define Vm   32000
#define Bn   2
#define Sn   1024
#define DHm  64
#define Mrows (Bn*Sn)   // 2048

typedef unsigned short ushort_t;
typedef __attribute__((ext_vector_type(8))) short          s16x8;
typedef __attribute__((ext_vector_type(8))) unsigned short u16x8;
typedef __attribute__((ext_vector_type(4))) float          f32x4;

__device__ __forceinline__ ushort_t f2bf(float x) {
    union { float f; unsigned u; } un; un.f = x;
    unsigned r = un.u + 0x7fffu + ((un.u >> 16) & 1u);
    return (ushort_t)(r >> 16);
}

// ---------------------------------------------------------------------------
// Stage TR rows x 64 k of bf16 from global (row-major, ld elements) into LDS
// tile (row stride 64 ushorts = 128B, 8 slots of 16B per row).
// LDS(r, s) holds global slot (s ^ (r&7))  [T2 swizzle via pre-swizzled source,
// global_load_lds writes linearly: lane i -> row i>>3, slot i&7].
// ---------------------------------------------------------------------------
template<int TR>
__device__ __forceinline__ void stage_tile(const ushort_t* __restrict__ src, int ld,
                                           ushort_t* lds, int k0, int w, int lane)
{
    #pragma unroll
    for (int c = 0; c < TR / 32; ++c) {
        const int rb = (w * (TR / 32) + c) * 8;           // wave-uniform row base
        const int r  = rb + (lane >> 3);
        const ushort_t* gp = src + (size_t)r * ld + k0
                           + (((lane & 7) ^ ((lane >> 3) & 7)) << 3);
        __builtin_amdgcn_global_load_lds(
            (const __attribute__((address_space(1))) void*)gp,
            (__attribute__((address_space(3))) void*)(lds + rb * 64),
            16, 0, 0);
    }
}

// read 8 bf16: LDS tile row r, global 16B-slot st (0..7)
__device__ __forceinline__ s16x8 ldrd(const ushort_t* lds, int r, int st)
{
    return *(const s16x8*)&lds[r * 64 + ((st ^ (r & 7)) << 3)];
}

// ---------------------------------------------------------------------------
// bf16 MFMA GEMM: C[M,N] = A[M,K] @ Bt[N,K]^T  (+bias) (+relu)
// A, Bt bf16 row-major; C fp32 (OBF=0) or bf16 (OBF=1).
// Tiles TMxTN (128x128 or 64x64), BK=64, 4 waves in a 2x2 wave grid.
// Batched over grid.z: z -> b=z/nh, h=z%nh with per-b/per-h element strides.
// Requires M%TM==0, N%TN==0, K%64==0.
// ---------------------------------------------------------------------------
template<int TM, int TN, bool OBF, bool BIAS, bool RELU>
__global__ __launch_bounds__(256) void gemm_bf(
    const ushort_t* __restrict__ A, const ushort_t* __restrict__ Bt,
    void* __restrict__ Cv, const float* __restrict__ bias,
    int K, int lda, int ldb, int ldc,
    long A_sb, long A_sh, long B_sb, long B_sh, long C_sb, long C_sh, int nh)
{
    constexpr int FI = TM / 32, FJ = TN / 32;   // 16x16 frags per wave
    __shared__ __align__(16) ushort_t As[TM * 64];
    __shared__ __align__(16) ushort_t Bs[TN * 64];

    const int z = blockIdx.z, b = z / nh, h = z - b * nh;
    A  += (size_t)b * A_sb + (size_t)h * A_sh;
    Bt += (size_t)b * B_sb + (size_t)h * B_sh;

    const int tid  = threadIdx.x;
    const int w    = tid >> 6, lane = tid & 63;
    const int m0   = blockIdx.y * TM, n0 = blockIdx.x * TN;
    const int rw   = (w >> 1) * (TM / 2);       // wave sub-tile row base
    const int cn   = (w & 1) * (TN / 2);        // wave sub-tile col base
    const int l15  = lane & 15, l4 = lane >> 4;

    f32x4 acc[FI][FJ] = {};

    for (int k0 = 0; k0 < K; k0 += 64) {
        stage_tile<TM>(A + (size_t)m0 * lda, lda, As, k0, w, lane);
        stage_tile<TN>(Bt + (size_t)n0 * ldb, ldb, Bs, k0, w, lane);
        __syncthreads();
        #pragma unroll
        for (int ks = 0; ks < 2; ++ks) {
            const int st = ks * 4 + l4;
            s16x8 av[FI], bv[FJ];
            #pragma unroll
            for (int i = 0; i < FI; ++i) av[i] = ldrd(As, rw + i * 16 + l15, st);
            #pragma unroll
            for (int j = 0; j < FJ; ++j) bv[j] = ldrd(Bs, cn + j * 16 + l15, st);
            #pragma unroll
            for (int i = 0; i < FI; ++i)
                #pragma unroll
                for (int j = 0; j < FJ; ++j)
                    acc[i][j] = __builtin_amdgcn_mfma_f32_16x16x32_bf16(
                                    av[i], bv[j], acc[i][j], 0, 0, 0);
        }
        __syncthreads();
    }

    // epilogue: D[col=lane&15, row=(lane>>4)*4 + r]  (m89-verified layout)
    const int colb = n0 + cn + l15;
    const int rowb = m0 + rw + (l4 << 2);
    float bvv[FJ];
    #pragma unroll
    for (int j = 0; j < FJ; ++j) bvv[j] = BIAS ? bias[colb + j * 16] : 0.f;

    if constexpr (OBF) {
        ushort_t* C = (ushort_t*)Cv + (size_t)b * C_sb + (size_t)h * C_sh;
        #pragma unroll
        for (int i = 0; i < FI; ++i)
            #pragma unroll
            for (int r = 0; r < 4; ++r) {
                const size_t row = rowb + i * 16 + r;
                #pragma unroll
                for (int j = 0; j < FJ; ++j) {
                    float v = acc[i][j][r] + bvv[j];
                    if (RELU) v = fmaxf(v, 0.f);
                    C[row * ldc + colb + j * 16] = f2bf(v);
                }
            }
    } else {
        float* C = (float*)Cv + (size_t)b * C_sb + (size_t)h * C_sh;
        #pragma unroll
        for (int i = 0; i < FI; ++i)
            #pragma unroll
            for (int r = 0; r < 4; ++r) {
                const size_t row = rowb + i * 16 + r;
                #pragma unroll
                for (int j = 0; j < FJ; ++j) {
                    float v = acc[i][j][r] + bvv[j];
                    if (RELU) v = fmaxf(v, 0.f);
                    C[row * ldc + colb + j * 16] = v;
                }
            }
    }
}

// ---------------------------------------------------------------------------
// Weight transpose+cvt: in fp32 [z][R][C] -> out bf16 [z][C][R]. grid(C/32,R/32,L)
// ---------------------------------------------------------------------------
__global__ __launch_bounds__(256) void wcvt_t(
    const float* __restrict__ in, ushort_t* __restrict__ out, int R, int C)
{
    in  += (size_t)blockIdx.z * R * C;
    out += (size_t)blockIdx.z * R * C;
    __shared__ float t[32][33];
    const int r0 = blockIdx.y * 32, c0 = blockIdx.x * 32;
    const int tid = threadIdx.x;
    const int r = tid >> 5, c = tid & 31;
    #pragma unroll
    for (int q = 0; q < 4; ++q)
        t[r + q * 8][c] = in[(size_t)(r0 + r + q * 8) * C + c0 + c];
    __syncthreads();
    const int c2 = tid >> 5, r2 = tid & 31;
    #pragma unroll
    for (int q = 0; q < 4; ++q)
        out[(size_t)(c0 + c2 + q * 8) * R + r0 + r2] = f2bf(t[r2][c2 + q * 8]);
}

// ---------------------------------------------------------------------------
// V transpose: V[b][s][h*64+d] (bf16, row stride ld) -> VT[z=b*nh+h][d][s]
// grid(Sn/64, 1, B*nh)
// ---------------------------------------------------------------------------
__global__ __launch_bounds__(256) void vtrans(
    const ushort_t* __restrict__ V, ushort_t* __restrict__ VT, int ld, int nh)
{
    const int z = blockIdx.z, b = z / nh, h = z - b * nh;
    const int s0 = blockIdx.x * 64;
    const ushort_t* src = V + (size_t)(b * Sn + s0) * ld + h * 64;
    ushort_t* dst = VT + (size_t)z * 64 * Sn;
    __shared__ ushort_t t[64][72];
    const int tid = threadIdx.x;
    #pragma unroll
    for (int q = 0; q < 2; ++q) {
        const int idx = tid + q * 256;           // 0..511
        const int s = idx >> 3, sl = idx & 7;
        *(u16x8*)&t[s][sl * 8] = *(const u16x8*)(src + (size_t)s * ld + sl * 8);
    }
    __syncthreads();
    #pragma unroll
    for (int q = 0; q < 2; ++q) {
        const int idx = tid + q * 256;
        const int d = idx >> 3, sl = idx & 7;
        u16x8 vv;
        #pragma unroll
        for (int u = 0; u < 8; ++u) vv[u] = t[sl * 8 + u][d];
        *(u16x8*)(dst + (size_t)d * Sn + s0 + sl * 8) = vv;
    }
}

// ---------------------------------------------------------------------------
// Softmax: read fp32 scores, *0.125, mask, softmax, write bf16 P.
// mode 0: pad mask (tok[k]==0); mode 1: causal. One block per row.
// ---------------------------------------------------------------------------
__global__ __launch_bounds__(256) void softmax_bf(
    const float* __restrict__ sc, ushort_t* __restrict__ P,
    const int* __restrict__ tok, int mode, int nh)
{
    const long row = blockIdx.x;                  // z*Sn + q
    const int q = (int)(row & (Sn - 1));
    const int z = (int)(row >> 10);
    const int b = z / nh;
    const float* p = sc + row * Sn;
    ushort_t* pp = P + row * Sn;
    const int t = threadIdx.x;

    float4 v4 = *(const float4*)(p + t * 4);
    float vv[4] = { v4.x * 0.125f, v4.y * 0.125f, v4.z * 0.125f, v4.w * 0.125f };
    if (mode == 0) {
        const int4 tv = *(const int4*)(tok + (size_t)b * Sn + t * 4);
        if (tv.x == 0) vv[0] = -1e9f;
        if (tv.y == 0) vv[1] = -1e9f;
        if (tv.z == 0) vv[2] = -1e9f;
        if (tv.w == 0) vv[3] = -1e9f;
    } else {
        #pragma unroll
        for (int r = 0; r < 4; ++r) if (t * 4 + r > q) vv[r] = -1e9f;
    }

    float mx = fmaxf(fmaxf(vv[0], vv[1]), fmaxf(vv[2], vv[3]));
    __shared__ float redm[4], reds[4];
    for (int off = 32; off; off >>= 1) mx = fmaxf(mx, __shfl_down(mx, off));
    const int lane = t & 63, w = t >> 6;
    if (lane == 0) redm[w] = mx;
    __syncthreads();
    mx = fmaxf(fmaxf(redm[0], redm[1]), fmaxf(redm[2], redm[3]));

    float sum = 0.f;
    #pragma unroll
    for (int r = 0; r < 4; ++r) { vv[r] = expf(vv[r] - mx); sum += vv[r]; }
    for (int off = 32; off; off >>= 1) sum += __shfl_down(sum, off);
    if (lane == 0) reds[w] = sum;
    __syncthreads();
    sum = reds[0] + reds[1] + reds[2] + reds[3];

    const float inv = 1.f / sum;
    ushort_t o[4];
    #pragma unroll
    for (int r = 0; r < 4; ++r) o[r] = f2bf(vv[r] * inv);
    *(uint2*)(pp + t * 4) = *(uint2*)o;
}

// ---------------------------------------------------------------------------
// x = layernorm(x + o)*s + b (fp32, in-place) and bf16 copy xbf.
// ---------------------------------------------------------------------------
__global__ __launch_bounds__(256) void add_ln(
    float* __restrict__ x, const float* __restrict__ o,
    const float* __restrict__ s, const float* __restrict__ bb,
    ushort_t* __restrict__ xbf)
{
    const long row = blockIdx.x;
    const int t = threadIdx.x;
    float* xr = x + row * Dm;
    const float* orr = o + row * Dm;
    float v0 = xr[t] + orr[t];
    float v1 = xr[t + 256] + orr[t + 256];

    float sum = v0 + v1, ssq = v0 * v0 + v1 * v1;
    __shared__ float red[8];
    for (int off = 32; off; off >>= 1) {
        sum += __shfl_down(sum, off);
        ssq += __shfl_down(ssq, off);
    }
    const int lane = t & 63, w = t >> 6;
    if (lane == 0) { red[w] = sum; red[4 + w] = ssq; }
    __syncthreads();
    sum = red[0] + red[1] + red[2] + red[3];
    ssq = red[4] + red[5] + red[6] + red[7];

    const float mean = sum * (1.f / Dm);
    const float var  = ssq * (1.f / Dm) - mean * mean;
    const float r = rsqrtf(var + 1e-5f);
    const float r0 = (v0 - mean) * r * s[t] + bb[t];
    const float r1 = (v1 - mean) * r * s[t + 256] + bb[t + 256];
    xr[t] = r0; xr[t + 256] = r1;
    xbf[row * Dm + t] = f2bf(r0);
    xbf[row * Dm + t + 256] = f2bf(r1);
}

// ---------------------------------------------------------------------------
// x[b,s,:] = emb[tok]*sqrt(D) + posenc(s,:)   (fp32 + bf16 copy)
// ---------------------------------------------------------------------------
__global__ __launch_bounds__(256) void embed_pe(
    const int* __restrict__ tok, const float* __restrict__ emb,
    float* __restrict__ out, ushort_t* __restrict__ outbf)
{
    const int bs = blockIdx.x;
    const int s = bs % Sn;
    const int t = threadIdx.x;
    const int token = tok[bs];
    #pragma unroll
    for (int r = 0; r < 2; ++r) {
        const int d = t + r * 256;
        const int i = d & ~1;
        const float ang = (float)s * powf(10000.0f, -(float)i / (float)Dm);
        const float pe = (d & 1) ? cosf(ang) : sinf(ang);
        const float v = emb[(size_t)token * Dm + d] * 22.627416997969522f + pe;
        out[(size_t)bs * Dm + d] = v;
        outbf[(size_t)bs * Dm + d] = f2bf(v);
    }
}

// ---------------------------------------------------------------------------
extern "C" void kernel_launch(void* const* d_in, const int* in_sizes, int n_in,
                              void* d_out, int out_size, void* d_ws, size_t ws_size,
                              hipStream_t stream)
{
    const int*   batch_src = (const int*)d_in[0];
    const int*   trg       = (const int*)d_in[1];
    const float* src_emb   = (const float*)d_in[2];
    const float* trg_emb   = (const float*)d_in[3];
    const float* fc_w      = (const float*)d_in[4];
    const float* fc_b      = (const float*)d_in[5];
    const float* enc_wqkv  = (const float*)d_in[6];
    const float* enc_wo    = (const float*)d_in[7];
    const float* enc_ln1s  = (const float*)d_in[8];
    const float* enc_ln1b  = (const float*)d_in[9];
    const float* enc_w1    = (const float*)d_in[10];
    const float* enc_b1    = (const float*)d_in[11];
    const float* enc_w2    = (const float*)d_in[12];
    const float* enc_b2    = (const float*)d_in[13];
    const float* enc_ln2s  = (const float*)d_in[14];
    const float* enc_ln2b  = (const float*)d_in[15];
    const float* dec_wqkv  = (const float*)d_in[16];
    const float* dec_wo    = (const float*)d_in[17];
    const float* dec_ln1s  = (const float*)d_in[18];
    const float* dec_ln1b  = (const float*)d_in[19];
    const float* dec_wq    = (const float*)d_in[20];
    const float* dec_wkv   = (const float*)d_in[21];
    const float* dec_woc   = (const float*)d_in[22];
    const float* dec_ln2s  = (const float*)d_in[23];
    const float* dec_ln2b  = (const float*)d_in[24];
    const float* dec_w1    = (const float*)d_in[25];
    const float* dec_b1    = (const float*)d_in[26];
    const float* dec_w2    = (const float*)d_in[27];
    const float* dec_b2    = (const float*)d_in[28];
    const float* dec_ln3s  = (const float*)d_in[29];
    const float* dec_ln3b  = (const float*)d_in[30];
    (void)in_sizes; (void)n_in; (void)out_size; (void)ws_size;

    // scores + P live in d_out (free scratch until final fc GEMM overwrites it)
    float*    SC = (float*)d_out;                                     // 64 MB
    ushort_t* P  = (ushort_t*)((char*)d_out + (((size_t)64) << 20));  // 32 MB

    char* p = (char*)d_ws;
    auto alloc = [&](size_t bytes) { char* r = p; p += (bytes + 255) & ~(size_t)255; return r; };
    float*    X     = (float*)alloc((size_t)Mrows * Dm * 4);
    float*    Y     = (float*)alloc((size_t)Mrows * Dm * 4);
    float*    O     = (float*)alloc((size_t)Mrows * Dm * 4);
    ushort_t* Xbf   = (ushort_t*)alloc((size_t)Mrows * Dm * 2);
    ushort_t* Ybf   = (ushort_t*)alloc((size_t)Mrows * Dm * 2);
    ushort_t* QKVbf = (ushort_t*)alloc((size_t)Mrows * 3 * Dm * 2);
    ushort_t* AObf  = (ushort_t*)alloc((size_t)Mrows * Dm * 2);
    ushort_t* FHbf  = (ushort_t*)alloc((size_t)Mrows * DFFm * 2);
    ushort_t* QCbf  = (ushort_t*)alloc((size_t)Mrows * Dm * 2);
    ushort_t* KVbf  = (ushort_t*)alloc((size_t)Mrows * 2 * Dm * 2);
    ushort_t* VT    = (ushort_t*)alloc((size_t)16 * DHm * Sn * 2);
    ushort_t* ewqkv_t = (ushort_t*)alloc((size_t)Ln * 3 * Dm * Dm * 2);
    ushort_t* ewo_t   = (ushort_t*)alloc((size_t)Ln * Dm * Dm * 2);
    ushort_t* ew1_t   = (ushort_t*)alloc((size_t)Ln * DFFm * Dm * 2);
    ushort_t* ew2_t   = (ushort_t*)alloc((size_t)Ln * Dm * DFFm * 2);
    ushort_t* dwqkv_t = (ushort_t*)alloc((size_t)Ln * 3 * Dm * Dm * 2);
    ushort_t* dwo_t   = (ushort_t*)alloc((size_t)Ln * Dm * Dm * 2);
    ushort_t* dwq_t   = (ushort_t*)alloc((size_t)Ln * Dm * Dm * 2);
    ushort_t* dwkv_t  = (ushort_t*)alloc((size_t)Ln * 2 * Dm * Dm * 2);
    ushort_t* dwoc_t  = (ushort_t*)alloc((size_t)Ln * Dm * Dm * 2);
    ushort_t* dw1_t   = (ushort_t*)alloc((size_t)Ln * DFFm * Dm * 2);
    ushort_t* dw2_t   = (ushort_t*)alloc((size_t)Ln * Dm * DFFm * 2);
    ushort_t* fcw_t   = (ushort_t*)alloc((size_t)Vm * Dm * 2);

    // ---------------- weight transpose+cvt (fp32 [K][N] -> bf16 [N][K]) -----
    wcvt_t<<<dim3(48, 16, 6),  256, 0, stream>>>(enc_wqkv, ewqkv_t, Dm, 3 * Dm);
    wcvt_t<<<dim3(16, 16, 6),  256, 0, stream>>>(enc_wo,   ewo_t,   Dm, Dm);
    wcvt_t<<<dim3(64, 16, 6),  256, 0, stream>>>(enc_w1,   ew1_t,   Dm, DFFm);
    wcvt_t<<<dim3(16, 64, 6),  256, 0, stream>>>(enc_w2,   ew2_t,   DFFm, Dm);
    wcvt_t<<<dim3(48, 16, 6),  256, 0, stream>>>(dec_wqkv, dwqkv_t, Dm, 3 * Dm);
    wcvt_t<<<dim3(16, 16, 6),  256, 0, stream>>>(dec_wo,   dwo_t,   Dm, Dm);
    wcvt_t<<<dim3(16, 16, 6),  256, 0, stream>>>(dec_wq,   dwq_t,   Dm, Dm);
    wcvt_t<<<dim3(32, 16, 6),  256, 0, stream>>>(dec_wkv,  dwkv_t,  Dm, 2 * Dm);
    wcvt_t<<<dim3(16, 16, 6),  256, 0, stream>>>(dec_woc,  dwoc_t,  Dm, Dm);
    wcvt_t<<<dim3(64, 16, 6),  256, 0, stream>>>(dec_w1,   dw1_t,   Dm, DFFm);
    wcvt_t<<<dim3(16, 64, 6),  256, 0, stream>>>(dec_w2,   dw2_t,   DFFm, Dm);
    wcvt_t<<<dim3(1000, 16, 1), 256, 0, stream>>>(fc_w,    fcw_t,   Dm, Vm);

    embed_pe<<<Mrows, 256, 0, stream>>>(batch_src, src_emb, X, Xbf);
    embed_pe<<<Mrows, 256, 0, stream>>>(trg,       trg_emb, Y, Ybf);

    const long SBH = (long)Sn * Sn;     // 1M: per-head score/P stride
    const long VTs = (long)DHm * Sn;    // 65536: per-head VT stride

    // --------------------------------- encoder ----------------------------
    for (int l = 0; l < Ln; ++l) {
        gemm_bf<128,128,true,false,false><<<dim3(12, 16, 1), 256, 0, stream>>>(
            Xbf, ewqkv_t + (size_t)l * 3 * Dm * Dm, QKVbf, nullptr,
            Dm, Dm, Dm, 3 * Dm, 0,0,0,0,0,0, 1);
        vtrans<<<dim3(16, 1, 16), 256, 0, stream>>>(QKVbf + 2 * Dm, VT, 3 * Dm, Hn);
        gemm_bf<128,128,false,false,false><<<dim3(8, 8, 16), 256, 0, stream>>>(
            QKVbf, QKVbf + Dm, SC, nullptr,
            DHm, 3 * Dm, 3 * Dm, Sn,
            (long)Sn * 3 * Dm, DHm, (long)Sn * 3 * Dm, DHm, Hn * SBH, SBH, Hn);
        softmax_bf<<<16 * Sn, 256, 0, stream>>>(SC, P, batch_src, 0, Hn);
        gemm_bf<64,64,true,false,false><<<dim3(1, 16, 16), 256, 0, stream>>>(
            P, VT, AObf, nullptr,
            Sn, Sn, Sn, Dm,
            Hn * SBH, SBH, Hn * VTs, VTs, (long)Sn * Dm, DHm, Hn);
        gemm_bf<64,64,false,false,false><<<dim3(8, 32, 1), 256, 0, stream>>>(
            AObf, ewo_t + (size_t)l * Dm * Dm, O, nullptr,
            Dm, Dm, Dm, Dm, 0,0,0,0,0,0, 1);
        add_ln<<<Mrows, 256, 0, stream>>>(X, O, enc_ln1s + l * Dm, enc_ln1b + l * Dm, Xbf);
        gemm_bf<128,128,true,true,true><<<dim3(16, 16, 1), 256, 0, stream>>>(
            Xbf, ew1_t + (size_t)l * DFFm * Dm, FHbf, enc_b1 + l * DFFm,
            Dm, Dm, Dm, DFFm, 0,0,0,0,0,0, 1);
        gemm_bf<64,64,false,true,false><<<dim3(8, 32, 1), 256, 0, stream>>>(
            FHbf, ew2_t + (size_t)l * Dm * DFFm, O, enc_b2 + l * Dm,
            DFFm, DFFm, DFFm, Dm, 0,0,0,0,0,0, 1);
        add_ln<<<Mrows, 256, 0, stream>>>(X, O, enc_ln2s + l * Dm, enc_ln2b + l * Dm, Xbf);
    }

    // --------------------------------- decoder ----------------------------
    for (int l = 0; l < Ln; ++l) {
        // self-attention (causal)
        gemm_bf<128,128,true,false,false><<<dim3(12, 16, 1), 256, 0, stream>>>(
            Ybf, dwqkv_t + (size_t)l * 3 * Dm * Dm, QKVbf, nullptr,
            Dm, Dm, Dm, 3 * Dm, 0,0,0,0,0,0, 1);
        vtrans<<<dim3(16, 1, 16), 256, 0, stream>>>(QKVbf + 2 * Dm, VT, 3 * Dm, Hn);
        gemm_bf<128,128,false,false,false><<<dim3(8, 8, 16), 256, 0, stream>>>(
            QKVbf, QKVbf + Dm, SC, nullptr,
            DHm, 3 * Dm, 3 * Dm, Sn,
            (long)Sn * 3 * Dm, DHm, (long)Sn * 3 * Dm, DHm, Hn * SBH, SBH, Hn);
        softmax_bf<<<16 * Sn, 256, 0, stream>>>(SC, P, nullptr, 1, Hn);
        gemm_bf<64,64,true,false,false><<<dim3(1, 16, 16), 256, 0, stream>>>(
            P, VT, AObf, nullptr,
            Sn, Sn, Sn, Dm,
            Hn * SBH, SBH, Hn * VTs, VTs, (long)Sn * Dm, DHm, Hn);
        gemm_bf<64,64,false,false,false><<<dim3(8, 32, 1), 256, 0, stream>>>(
            AObf, dwo_t + (size_t)l * Dm * Dm, O, nullptr,
            Dm, Dm, Dm, Dm, 0,0,0,0,0,0, 1);
        add_ln<<<Mrows, 256, 0, stream>>>(Y, O, dec_ln1s + l * Dm, dec_ln1b + l * Dm, Ybf);

        // cross-attention (pad mask)
        gemm_bf<64,64,true,false,false><<<dim3(8, 32, 1), 256, 0, stream>>>(
            Ybf, dwq_t + (size_t)l * Dm * Dm, QCbf, nullptr,
            Dm, Dm, Dm, Dm, 0,0,0,0,0,0, 1);
        gemm_bf<128,128,true,false,false><<<dim3(8, 16, 1), 256, 0, stream>>>(
            Xbf, dwkv_t + (size_t)l * 2 * Dm * Dm, KVbf, nullptr,
            Dm, Dm, Dm, 2 * Dm, 0,0,0,0,0,0, 1);
        vtrans<<<dim3(16, 1, 16), 256, 0, stream>>>(KVbf + Dm, VT, 2 * Dm, Hn);
        gemm_bf<128,128,false,false,false><<<dim3(8, 8, 16), 256, 0, stream>>>(
            QCbf, KVbf, SC, nullptr,
            DHm, Dm, 2 * Dm, Sn,
            (long)Sn * Dm, DHm, (long)Sn * 2 * Dm, DHm, Hn * SBH, SBH, Hn);
        softmax_bf<<<16 * Sn, 256, 0, stream>>>(SC, P, batch_src, 0, Hn);
        gemm_bf<64,64,true,false,false><<<dim3(1, 16, 16), 256, 0, stream>>>(
            P, VT, AObf, nullptr,
            Sn, Sn, Sn, Dm,
            Hn * SBH, SBH, Hn * VTs, VTs, (long)Sn * Dm, DHm, Hn);
        gemm_bf<64,64,false,false,false><<<dim3(8, 32, 1), 256, 0, stream>>>(
            AObf, dwoc_t + (size_t)l * Dm * Dm, O, nullptr,
            Dm, Dm, Dm, Dm, 0,0,0,0,0,0, 1);
        add_ln<<<Mrows, 256, 0, stream>>>(Y, O, dec_ln2s + l * Dm, dec_ln2b + l * Dm, Ybf);

        // feed-forward
        gemm_bf<128,128,true,true,true><<<dim3(16, 16, 1), 256, 0, stream>>>(
            Ybf, dw1_t + (size_t)l * DFFm * Dm, FHbf, dec_b1 + l * DFFm,
            Dm, Dm, Dm, DFFm, 0,0,0,0,0,0, 1);
        gemm_bf<64,64,false,true,false><<<dim3(8, 32, 1), 256, 0, stream>>>(
            FHbf, dw2_t + (size_t)l * Dm * DFFm, O, dec_b2 + l * Dm,
            DFFm, DFFm, DFFm, Dm, 0,0,0,0,0,0, 1);
        add_ln<<<Mrows, 256, 0, stream>>>(Y, O, dec_ln3s + l * Dm, dec_ln3b + l * Dm, Ybf);
    }

    // final projection to vocab (overwrites the SC/P scratch region of d_out)
    gemm_bf<128,128,false,true,false><<<dim3(Vm / 128, 16, 1), 256, 0, stream>>>(
        Ybf, fcw_t, (float*)d_out, fc_b,
        Dm, Dm, Dm, Vm, 0,0,0,0,0,0, 1);
}

// Round 4
// 1938.755 us; speedup vs baseline: 3.9182x; 1.2328x over previous
//
#include <hip/hip_runtime.h>
#include <cmath>

#define Dm   512
#define Hn   8
#define Ln   6
#define DFFm 2048
#define Vm   32000
#define Bn   2
#define Sn   1024
#define DHm  64
#define Mrows (Bn*Sn)   // 2048

typedef unsigned short ushort_t;
typedef __attribute__((ext_vector_type(8))) short          s16x8;
typedef __attribute__((ext_vector_type(8))) unsigned short u16x8;
typedef __attribute__((ext_vector_type(4))) float          f32x4;

__device__ __forceinline__ ushort_t f2bf(float x) {
    union { float f; unsigned u; } un; un.f = x;
    unsigned r = un.u + 0x7fffu + ((un.u >> 16) & 1u);
    return (ushort_t)(r >> 16);
}

// ---------------------------------------------------------------------------
// Stage TR rows x 64 k of bf16 from global (row-major, ld elements) into LDS
// tile (row stride 64 ushorts = 128B, 8 slots of 16B per row).
// LDS(r, sl) holds global slot (sl ^ (r&7))  [T2 swizzle via pre-swizzled
// source; global_load_lds writes linearly: lane i -> row i>>3, slot i&7].
// ---------------------------------------------------------------------------
template<int TR>
__device__ __forceinline__ void stage_tile(const ushort_t* __restrict__ src, int ld,
                                           ushort_t* lds, int k0, int w, int lane)
{
    #pragma unroll
    for (int c = 0; c < TR / 32; ++c) {
        const int rb = (w * (TR / 32) + c) * 8;           // wave-uniform row base
        const int r  = rb + (lane >> 3);
        const ushort_t* gp = src + (size_t)r * ld + k0
                           + (((lane & 7) ^ ((lane >> 3) & 7)) << 3);
        __builtin_amdgcn_global_load_lds(
            (const __attribute__((address_space(1))) void*)gp,
            (__attribute__((address_space(3))) void*)(lds + rb * 64),
            16, 0, 0);
    }
}

// read 8 bf16: LDS tile row r, logical 16B-slot st (0..7)
__device__ __forceinline__ s16x8 ldrd(const ushort_t* lds, int r, int st)
{
    return *(const s16x8*)&lds[r * 64 + ((st ^ (r & 7)) << 3)];
}

// ---------------------------------------------------------------------------
// bf16 MFMA GEMM: C[M,N] = A[M,K] @ Bt[N,K]^T  (+bias) (+relu)
// A, Bt bf16 row-major; C fp32 (OBF=0) or bf16 (OBF=1).
// Tiles TMxTN, BK=64, 4 waves in a 2x2 wave grid.
// Batched over grid.z: z -> b=z/nh, h=z%nh with per-b/per-h element strides.
// ---------------------------------------------------------------------------
template<int TM, int TN, bool OBF, bool BIAS, bool RELU>
__global__ __launch_bounds__(256) void gemm_bf(
    const ushort_t* __restrict__ A, const ushort_t* __restrict__ Bt,
    void* __restrict__ Cv, const float* __restrict__ bias,
    int K, int lda, int ldb, int ldc,
    long A_sb, long A_sh, long B_sb, long B_sh, long C_sb, long C_sh, int nh)
{
    constexpr int FI = TM / 32, FJ = TN / 32;   // 16x16 frags per wave
    __shared__ __align__(16) ushort_t As[TM * 64];
    __shared__ __align__(16) ushort_t Bs[TN * 64];

    const int z = blockIdx.z, b = z / nh, h = z - b * nh;
    A  += (size_t)b * A_sb + (size_t)h * A_sh;
    Bt += (size_t)b * B_sb + (size_t)h * B_sh;

    const int tid  = threadIdx.x;
    const int w    = tid >> 6, lane = tid & 63;
    const int m0   = blockIdx.y * TM, n0 = blockIdx.x * TN;
    const int rw   = (w >> 1) * (TM / 2);       // wave sub-tile row base
    const int cn   = (w & 1) * (TN / 2);        // wave sub-tile col base
    const int l15  = lane & 15, l4 = lane >> 4;

    f32x4 acc[FI][FJ] = {};

    for (int k0 = 0; k0 < K; k0 += 64) {
        stage_tile<TM>(A + (size_t)m0 * lda, lda, As, k0, w, lane);
        stage_tile<TN>(Bt + (size_t)n0 * ldb, ldb, Bs, k0, w, lane);
        __syncthreads();
        #pragma unroll
        for (int ks = 0; ks < 2; ++ks) {
            const int st = ks * 4 + l4;
            s16x8 av[FI], bv[FJ];
            #pragma unroll
            for (int i = 0; i < FI; ++i) av[i] = ldrd(As, rw + i * 16 + l15, st);
            #pragma unroll
            for (int j = 0; j < FJ; ++j) bv[j] = ldrd(Bs, cn + j * 16 + l15, st);
            #pragma unroll
            for (int i = 0; i < FI; ++i)
                #pragma unroll
                for (int j = 0; j < FJ; ++j)
                    acc[i][j] = __builtin_amdgcn_mfma_f32_16x16x32_bf16(
                                    av[i], bv[j], acc[i][j], 0, 0, 0);
        }
        __syncthreads();
    }

    // epilogue: D[col=lane&15, row=(lane>>4)*4 + r]  (m89-verified layout)
    const int colb = n0 + cn + l15;
    const int rowb = m0 + rw + (l4 << 2);
    float bvv[FJ];
    #pragma unroll
    for (int j = 0; j < FJ; ++j) bvv[j] = BIAS ? bias[colb + j * 16] : 0.f;

    if constexpr (OBF) {
        ushort_t* C = (ushort_t*)Cv + (size_t)b * C_sb + (size_t)h * C_sh;
        #pragma unroll
        for (int i = 0; i < FI; ++i)
            #pragma unroll
            for (int r = 0; r < 4; ++r) {
                const size_t row = rowb + i * 16 + r;
                #pragma unroll
                for (int j = 0; j < FJ; ++j) {
                    float v = acc[i][j][r] + bvv[j];
                    if (RELU) v = fmaxf(v, 0.f);
                    C[row * ldc + colb + j * 16] = f2bf(v);
                }
            }
    } else {
        float* C = (float*)Cv + (size_t)b * C_sb + (size_t)h * C_sh;
        #pragma unroll
        for (int i = 0; i < FI; ++i)
            #pragma unroll
            for (int r = 0; r < 4; ++r) {
                const size_t row = rowb + i * 16 + r;
                #pragma unroll
                for (int j = 0; j < FJ; ++j) {
                    float v = acc[i][j][r] + bvv[j];
                    if (RELU) v = fmaxf(v, 0.f);
                    C[row * ldc + colb + j * 16] = v;
                }
            }
    }
}

// ---------------------------------------------------------------------------
// Flash-fused attention. One block = 4 waves = 64 q-rows of one (b,h).
// Q from Qp (row-major, ldq, head offset h*64); K from Kp (ldk likewise);
// V^T from VTp[z][d][s] (ld = Sn). Output AO[b*Sn+q][h*64+d] bf16.
// MODE 0: pad mask (tok[k]==0 blocked); MODE 1: causal.
// ---------------------------------------------------------------------------
template<int MODE>
__global__ __launch_bounds__(256) void flash_attn(
    const ushort_t* __restrict__ Qp, const ushort_t* __restrict__ Kp,
    const ushort_t* __restrict__ VTp, ushort_t* __restrict__ AO,
    const int* __restrict__ tok, int ldq, int ldk)
{
    __shared__ __align__(16) ushort_t Ks[2][64 * 64];
    __shared__ __align__(16) ushort_t Vs[2][64 * 64];
    __shared__ __align__(16) ushort_t Ps[4][16 * 64];
    __shared__ float msk[Sn];

    const int z = blockIdx.y, b = z >> 3, h = z & 7;
    const int qb = blockIdx.x * 64;
    const int tid = threadIdx.x, w = tid >> 6, lane = tid & 63;
    const int l15 = lane & 15, l4 = lane >> 4;

    const ushort_t* Qbase = Qp + (size_t)b * Sn * ldq + h * 64;
    const ushort_t* Kbase = Kp + (size_t)b * Sn * ldk + h * 64;
    const ushort_t* Vbase = VTp + (size_t)z * 64 * Sn;
    ushort_t* Obase = AO + ((size_t)(b * Sn + qb)) * Dm + h * 64;

    if (MODE == 0) {
        const int* tb = tok + (size_t)b * Sn;
        for (int i = tid; i < Sn; i += 256) msk[i] = (tb[i] == 0) ? 1.f : 0.f;
    }

    // Q fragments in registers (A-operand layout)
    const int qrow = qb + w * 16 + l15;
    s16x8 qv[2];
    qv[0] = *(const s16x8*)(Qbase + (size_t)qrow * ldq + l4 * 8);
    qv[1] = *(const s16x8*)(Qbase + (size_t)qrow * ldq + 32 + l4 * 8);

    f32x4 o[4] = {};
    float m[4], lsum[4];
    #pragma unroll
    for (int r = 0; r < 4; ++r) { m[r] = -1e30f; lsum[r] = 0.f; }

    const int nt = (MODE == 1) ? (qb / 64 + 1) : (Sn / 64);

    stage_tile<64>(Kbase, ldk, Ks[0], 0, w, lane);
    stage_tile<64>(Vbase, Sn, Vs[0], 0, w, lane);
    __syncthreads();

    for (int kt = 0; kt < nt; ++kt) {
        const int cur = kt & 1;
        if (kt + 1 < nt) {
            stage_tile<64>(Kbase + (size_t)((kt + 1) * 64) * ldk, ldk, Ks[cur ^ 1], 0, w, lane);
            stage_tile<64>(Vbase, Sn, Vs[cur ^ 1], (kt + 1) * 64, w, lane);
        }

        // S = Q @ K^T
        f32x4 s[4] = {};
        #pragma unroll
        for (int ks = 0; ks < 2; ++ks) {
            const int st = ks * 4 + l4;
            #pragma unroll
            for (int j = 0; j < 4; ++j) {
                s16x8 bv = ldrd(Ks[cur], j * 16 + l15, st);
                s[j] = __builtin_amdgcn_mfma_f32_16x16x32_bf16(qv[ks], bv, s[j], 0, 0, 0);
            }
        }

        // scale + mask
        #pragma unroll
        for (int j = 0; j < 4; ++j) {
            const int col = kt * 64 + j * 16 + l15;
            #pragma unroll
            for (int r = 0; r < 4; ++r) {
                float v = s[j][r] * 0.125f;
                if (MODE == 0) { if (msk[col] != 0.f) v = -1e9f; }
                else           { if (col > qb + w * 16 + l4 * 4 + r) v = -1e9f; }
                s[j][r] = v;
            }
        }

        // row max over the 64 tile cols (4 frags x 16 lanes)
        float mt[4];
        #pragma unroll
        for (int r = 0; r < 4; ++r)
            mt[r] = fmaxf(fmaxf(s[0][r], s[1][r]), fmaxf(s[2][r], s[3][r]));
        #pragma unroll
        for (int mk = 1; mk < 16; mk <<= 1)
            #pragma unroll
            for (int r = 0; r < 4; ++r)
                mt[r] = fmaxf(mt[r], __shfl_xor(mt[r], mk));

        float al[4];
        #pragma unroll
        for (int r = 0; r < 4; ++r) {
            const float mn = fmaxf(m[r], mt[r]);
            al[r] = __expf(m[r] - mn);
            m[r] = mn;
        }

        // P = exp(S - m); write bf16 into per-wave swizzled LDS tile
        float rs[4] = {0.f, 0.f, 0.f, 0.f};
        ushort_t* pw = Ps[w];
        #pragma unroll
        for (int j = 0; j < 4; ++j) {
            const int slot = j * 2 + (l15 >> 3), e = l15 & 7;
            #pragma unroll
            for (int r = 0; r < 4; ++r) {
                const float pvv = __expf(s[j][r] - m[r]);
                rs[r] += pvv;
                const int row = l4 * 4 + r;
                pw[row * 64 + ((slot ^ (row & 7)) << 3) + e] = f2bf(pvv);
            }
        }
        #pragma unroll
        for (int mk = 1; mk < 16; mk <<= 1)
            #pragma unroll
            for (int r = 0; r < 4; ++r)
                rs[r] += __shfl_xor(rs[r], mk);
        #pragma unroll
        for (int r = 0; r < 4; ++r) lsum[r] = lsum[r] * al[r] + rs[r];

        // rescale O, then O += P @ V
        #pragma unroll
        for (int jd = 0; jd < 4; ++jd)
            #pragma unroll
            for (int r = 0; r < 4; ++r)
                o[jd][r] *= al[r];
        #pragma unroll
        for (int ks2 = 0; ks2 < 2; ++ks2) {
            const int st2 = ks2 * 4 + l4;
            s16x8 pa = ldrd(pw, l15, st2);
            #pragma unroll
            for (int jd = 0; jd < 4; ++jd) {
                s16x8 bv2 = ldrd(Vs[cur], jd * 16 + l15, st2);
                o[jd] = __builtin_amdgcn_mfma_f32_16x16x32_bf16(pa, bv2, o[jd], 0, 0, 0);
            }
        }
        __syncthreads();
    }

    // epilogue: O /= l, write bf16
    #pragma unroll
    for (int r = 0; r < 4; ++r) lsum[r] = 1.f / lsum[r];
    #pragma unroll
    for (int jd = 0; jd < 4; ++jd)
        #pragma unroll
        for (int r = 0; r < 4; ++r)
            Obase[(size_t)(w * 16 + l4 * 4 + r) * Dm + jd * 16 + l15] =
                f2bf(o[jd][r] * lsum[r]);
}

// ---------------------------------------------------------------------------
// Weight transpose+cvt: in fp32 [z][R][C] -> out bf16 [z][C][R]. grid(C/32,R/32,L)
// ---------------------------------------------------------------------------
__global__ __launch_bounds__(256) void wcvt_t(
    const float* __restrict__ in, ushort_t* __restrict__ out, int R, int C)
{
    in  += (size_t)blockIdx.z * R * C;
    out += (size_t)blockIdx.z * R * C;
    __shared__ float t[32][33];
    const int r0 = blockIdx.y * 32, c0 = blockIdx.x * 32;
    const int tid = threadIdx.x;
    const int r = tid >> 5, c = tid & 31;
    #pragma unroll
    for (int q = 0; q < 4; ++q)
        t[r + q * 8][c] = in[(size_t)(r0 + r + q * 8) * C + c0 + c];
    __syncthreads();
    const int c2 = tid >> 5, r2 = tid & 31;
    #pragma unroll
    for (int q = 0; q < 4; ++q)
        out[(size_t)(c0 + c2 + q * 8) * R + r0 + r2] = f2bf(t[r2][c2 + q * 8]);
}

// ---------------------------------------------------------------------------
// V transpose: V[b][s][h*64+d] (bf16, row stride ld) -> VT[z=b*nh+h][d][s]
// grid(Sn/64, 1, B*nh)
// ---------------------------------------------------------------------------
__global__ __launch_bounds__(256) void vtrans(
    const ushort_t* __restrict__ V, ushort_t* __restrict__ VT, int ld, int nh)
{
    const int z = blockIdx.z, b = z / nh, h = z - b * nh;
    const int s0 = blockIdx.x * 64;
    const ushort_t* src = V + (size_t)(b * Sn + s0) * ld + h * 64;
    ushort_t* dst = VT + (size_t)z * 64 * Sn;
    __shared__ ushort_t t[64][72];
    const int tid = threadIdx.x;
    #pragma unroll
    for (int q = 0; q < 2; ++q) {
        const int idx = tid + q * 256;           // 0..511
        const int s = idx >> 3, sl = idx & 7;
        *(u16x8*)&t[s][sl * 8] = *(const u16x8*)(src + (size_t)s * ld + sl * 8);
    }
    __syncthreads();
    #pragma unroll
    for (int q = 0; q < 2; ++q) {
        const int idx = tid + q * 256;
        const int d = idx >> 3, sl = idx & 7;
        u16x8 vv;
        #pragma unroll
        for (int u = 0; u < 8; ++u) vv[u] = t[sl * 8 + u][d];
        *(u16x8*)(dst + (size_t)d * Sn + s0 + sl * 8) = vv;
    }
}

// ---------------------------------------------------------------------------
// x = layernorm(x + o)*s + b (fp32, in-place) and bf16 copy xbf.
// ---------------------------------------------------------------------------
__global__ __launch_bounds__(256) void add_ln(
    float* __restrict__ x, const float* __restrict__ o,
    const float* __restrict__ s, const float* __restrict__ bb,
    ushort_t* __restrict__ xbf)
{
    const long row = blockIdx.x;
    const int t = threadIdx.x;
    float* xr = x + row * Dm;
    const float* orr = o + row * Dm;
    float v0 = xr[t] + orr[t];
    float v1 = xr[t + 256] + orr[t + 256];

    float sum = v0 + v1, ssq = v0 * v0 + v1 * v1;
    __shared__ float red[8];
    for (int off = 32; off; off >>= 1) {
        sum += __shfl_down(sum, off);
        ssq += __shfl_down(ssq, off);
    }
    const int lane = t & 63, w = t >> 6;
    if (lane == 0) { red[w] = sum; red[4 + w] = ssq; }
    __syncthreads();
    sum = red[0] + red[1] + red[2] + red[3];
    ssq = red[4] + red[5] + red[6] + red[7];

    const float mean = sum * (1.f / Dm);
    const float var  = ssq * (1.f / Dm) - mean * mean;
    const float r = rsqrtf(var + 1e-5f);
    const float r0 = (v0 - mean) * r * s[t] + bb[t];
    const float r1 = (v1 - mean) * r * s[t + 256] + bb[t + 256];
    xr[t] = r0; xr[t + 256] = r1;
    xbf[row * Dm + t] = f2bf(r0);
    xbf[row * Dm + t + 256] = f2bf(r1);
}

// ---------------------------------------------------------------------------
// x[b,s,:] = emb[tok]*sqrt(D) + posenc(s,:)   (fp32 + bf16 copy)
// ---------------------------------------------------------------------------
__global__ __launch_bounds__(256) void embed_pe(
    const int* __restrict__ tok, const float* __restrict__ emb,
    float* __restrict__ out, ushort_t* __restrict__ outbf)
{
    const int bs = blockIdx.x;
    const int s = bs % Sn;
    const int t = threadIdx.x;
    const int token = tok[bs];
    #pragma unroll
    for (int r = 0; r < 2; ++r) {
        const int d = t + r * 256;
        const int i = d & ~1;
        const float ang = (float)s * powf(10000.0f, -(float)i / (float)Dm);
        const float pe = (d & 1) ? cosf(ang) : sinf(ang);
        const float v = emb[(size_t)token * Dm + d] * 22.627416997969522f + pe;
        out[(size_t)bs * Dm + d] = v;
        outbf[(size_t)bs * Dm + d] = f2bf(v);
    }
}

// ---------------------------------------------------------------------------
extern "C" void kernel_launch(void* const* d_in, const int* in_sizes, int n_in,
                              void* d_out, int out_size, void* d_ws, size_t ws_size,
                              hipStream_t stream)
{
    const int*   batch_src = (const int*)d_in[0];
    const int*   trg       = (const int*)d_in[1];
    const float* src_emb   = (const float*)d_in[2];
    const float* trg_emb   = (const float*)d_in[3];
    const float* fc_w      = (const float*)d_in[4];
    const float* fc_b      = (const float*)d_in[5];
    const float* enc_wqkv  = (const float*)d_in[6];
    const float* enc_wo    = (const float*)d_in[7];
    const float* enc_ln1s  = (const float*)d_in[8];
    const float* enc_ln1b  = (const float*)d_in[9];
    const float* enc_w1    = (const float*)d_in[10];
    const float* enc_b1    = (const float*)d_in[11];
    const float* enc_w2    = (const float*)d_in[12];
    const float* enc_b2    = (const float*)d_in[13];
    const float* enc_ln2s  = (const float*)d_in[14];
    const float* enc_ln2b  = (const float*)d_in[15];
    const float* dec_wqkv  = (const float*)d_in[16];
    const float* dec_wo    = (const float*)d_in[17];
    const float* dec_ln1s  = (const float*)d_in[18];
    const float* dec_ln1b  = (const float*)d_in[19];
    const float* dec_wq    = (const float*)d_in[20];
    const float* dec_wkv   = (const float*)d_in[21];
    const float* dec_woc   = (const float*)d_in[22];
    const float* dec_ln2s  = (const float*)d_in[23];
    const float* dec_ln2b  = (const float*)d_in[24];
    const float* dec_w1    = (const float*)d_in[25];
    const float* dec_b1    = (const float*)d_in[26];
    const float* dec_w2    = (const float*)d_in[27];
    const float* dec_b2    = (const float*)d_in[28];
    const float* dec_ln3s  = (const float*)d_in[29];
    const float* dec_ln3b  = (const float*)d_in[30];
    (void)in_sizes; (void)n_in; (void)out_size; (void)ws_size;

    char* p = (char*)d_ws;
    auto alloc = [&](size_t bytes) { char* r = p; p += (bytes + 255) & ~(size_t)255; return r; };
    float*    X     = (float*)alloc((size_t)Mrows * Dm * 4);
    float*    Y     = (float*)alloc((size_t)Mrows * Dm * 4);
    float*    O     = (float*)alloc((size_t)Mrows * Dm * 4);
    ushort_t* Xbf   = (ushort_t*)alloc((size_t)Mrows * Dm * 2);
    ushort_t* Ybf   = (ushort_t*)alloc((size_t)Mrows * Dm * 2);
    ushort_t* QKVbf = (ushort_t*)alloc((size_t)Mrows * 3 * Dm * 2);
    ushort_t* AObf  = (ushort_t*)alloc((size_t)Mrows * Dm * 2);
    ushort_t* FHbf  = (ushort_t*)alloc((size_t)Mrows * DFFm * 2);
    ushort_t* QCbf  = (ushort_t*)alloc((size_t)Mrows * Dm * 2);
    ushort_t* KVbf  = (ushort_t*)alloc((size_t)Mrows * 2 * Dm * 2);
    ushort_t* VT    = (ushort_t*)alloc((size_t)16 * DHm * Sn * 2);
    ushort_t* ewqkv_t = (ushort_t*)alloc((size_t)Ln * 3 * Dm * Dm * 2);
    ushort_t* ewo_t   = (ushort_t*)alloc((size_t)Ln * Dm * Dm * 2);
    ushort_t* ew1_t   = (ushort_t*)alloc((size_t)Ln * DFFm * Dm * 2);
    ushort_t* ew2_t   = (ushort_t*)alloc((size_t)Ln * Dm * DFFm * 2);
    ushort_t* dwqkv_t = (ushort_t*)alloc((size_t)Ln * 3 * Dm * Dm * 2);
    ushort_t* dwo_t   = (ushort_t*)alloc((size_t)Ln * Dm * Dm * 2);
    ushort_t* dwq_t   = (ushort_t*)alloc((size_t)Ln * Dm * Dm * 2);
    ushort_t* dwkv_t  = (ushort_t*)alloc((size_t)Ln * 2 * Dm * Dm * 2);
    ushort_t* dwoc_t  = (ushort_t*)alloc((size_t)Ln * Dm * Dm * 2);
    ushort_t* dw1_t   = (ushort_t*)alloc((size_t)Ln * DFFm * Dm * 2);
    ushort_t* dw2_t   = (ushort_t*)alloc((size_t)Ln * Dm * DFFm * 2);
    ushort_t* fcw_t   = (ushort_t*)alloc((size_t)Vm * Dm * 2);

    // ---------------- weight transpose+cvt (fp32 [K][N] -> bf16 [N][K]) -----
    wcvt_t<<<dim3(48, 16, 6),  256, 0, stream>>>(enc_wqkv, ewqkv_t, Dm, 3 * Dm);
    wcvt_t<<<dim3(16, 16, 6),  256, 0, stream>>>(enc_wo,   ewo_t,   Dm, Dm);
    wcvt_t<<<dim3(64, 16, 6),  256, 0, stream>>>(enc_w1,   ew1_t,   Dm, DFFm);
    wcvt_t<<<dim3(16, 64, 6),  256, 0, stream>>>(enc_w2,   ew2_t,   DFFm, Dm);
    wcvt_t<<<dim3(48, 16, 6),  256, 0, stream>>>(dec_wqkv, dwqkv_t, Dm, 3 * Dm);
    wcvt_t<<<dim3(16, 16, 6),  256, 0, stream>>>(dec_wo,   dwo_t,   Dm, Dm);
    wcvt_t<<<dim3(16, 16, 6),  256, 0, stream>>>(dec_wq,   dwq_t,   Dm, Dm);
    wcvt_t<<<dim3(32, 16, 6),  256, 0, stream>>>(dec_wkv,  dwkv_t,  Dm, 2 * Dm);
    wcvt_t<<<dim3(16, 16, 6),  256, 0, stream>>>(dec_woc,  dwoc_t,  Dm, Dm);
    wcvt_t<<<dim3(64, 16, 6),  256, 0, stream>>>(dec_w1,   dw1_t,   Dm, DFFm);
    wcvt_t<<<dim3(16, 64, 6),  256, 0, stream>>>(dec_w2,   dw2_t,   DFFm, Dm);
    wcvt_t<<<dim3(1000, 16, 1), 256, 0, stream>>>(fc_w,    fcw_t,   Dm, Vm);

    embed_pe<<<Mrows, 256, 0, stream>>>(batch_src, src_emb, X, Xbf);
    embed_pe<<<Mrows, 256, 0, stream>>>(trg,       trg_emb, Y, Ybf);

    // --------------------------------- encoder ----------------------------
    for (int l = 0; l < Ln; ++l) {
        gemm_bf<64,128,true,false,false><<<dim3(12, 32, 1), 256, 0, stream>>>(
            Xbf, ewqkv_t + (size_t)l * 3 * Dm * Dm, QKVbf, nullptr,
            Dm, Dm, Dm, 3 * Dm, 0,0,0,0,0,0, 1);
        vtrans<<<dim3(16, 1, 16), 256, 0, stream>>>(QKVbf + 2 * Dm, VT, 3 * Dm, Hn);
        flash_attn<0><<<dim3(16, 16), 256, 0, stream>>>(
            QKVbf, QKVbf + Dm, VT, AObf, batch_src, 3 * Dm, 3 * Dm);
        gemm_bf<64,64,false,false,false><<<dim3(8, 32, 1), 256, 0, stream>>>(
            AObf, ewo_t + (size_t)l * Dm * Dm, O, nullptr,
            Dm, Dm, Dm, Dm, 0,0,0,0,0,0, 1);
        add_ln<<<Mrows, 256, 0, stream>>>(X, O, enc_ln1s + l * Dm, enc_ln1b + l * Dm, Xbf);
        gemm_bf<64,128,true,true,true><<<dim3(16, 32, 1), 256, 0, stream>>>(
            Xbf, ew1_t + (size_t)l * DFFm * Dm, FHbf, enc_b1 + l * DFFm,
            Dm, Dm, Dm, DFFm, 0,0,0,0,0,0, 1);
        gemm_bf<64,64,false,true,false><<<dim3(8, 32, 1), 256, 0, stream>>>(
            FHbf, ew2_t + (size_t)l * Dm * DFFm, O, enc_b2 + l * Dm,
            DFFm, DFFm, DFFm, Dm, 0,0,0,0,0,0, 1);
        add_ln<<<Mrows, 256, 0, stream>>>(X, O, enc_ln2s + l * Dm, enc_ln2b + l * Dm, Xbf);
    }

    // --------------------------------- decoder ----------------------------
    for (int l = 0; l < Ln; ++l) {
        // self-attention (causal)
        gemm_bf<64,128,true,false,false><<<dim3(12, 32, 1), 256, 0, stream>>>(
            Ybf, dwqkv_t + (size_t)l * 3 * Dm * Dm, QKVbf, nullptr,
            Dm, Dm, Dm, 3 * Dm, 0,0,0,0,0,0, 1);
        vtrans<<<dim3(16, 1, 16), 256, 0, stream>>>(QKVbf + 2 * Dm, VT, 3 * Dm, Hn);
        flash_attn<1><<<dim3(16, 16), 256, 0, stream>>>(
            QKVbf, QKVbf + Dm, VT, AObf, nullptr, 3 * Dm, 3 * Dm);
        gemm_bf<64,64,false,false,false><<<dim3(8, 32, 1), 256, 0, stream>>>(
            AObf, dwo_t + (size_t)l * Dm * Dm, O, nullptr,
            Dm, Dm, Dm, Dm, 0,0,0,0,0,0, 1);
        add_ln<<<Mrows, 256, 0, stream>>>(Y, O, dec_ln1s + l * Dm, dec_ln1b + l * Dm, Ybf);

        // cross-attention (pad mask)
        gemm_bf<64,64,true,false,false><<<dim3(8, 32, 1), 256, 0, stream>>>(
            Ybf, dwq_t + (size_t)l * Dm * Dm, QCbf, nullptr,
            Dm, Dm, Dm, Dm, 0,0,0,0,0,0, 1);
        gemm_bf<64,128,true,false,false><<<dim3(8, 32, 1), 256, 0, stream>>>(
            Xbf, dwkv_t + (size_t)l * 2 * Dm * Dm, KVbf, nullptr,
            Dm, Dm, Dm, 2 * Dm, 0,0,0,0,0,0, 1);
        vtrans<<<dim3(16, 1, 16), 256, 0, stream>>>(KVbf + Dm, VT, 2 * Dm, Hn);
        flash_attn<0><<<dim3(16, 16), 256, 0, stream>>>(
            QCbf, KVbf, VT, AObf, batch_src, Dm, 2 * Dm);
        gemm_bf<64,64,false,false,false><<<dim3(8, 32, 1), 256, 0, stream>>>(
            AObf, dwoc_t + (size_t)l * Dm * Dm, O, nullptr,
            Dm, Dm, Dm, Dm, 0,0,0,0,0,0, 1);
        add_ln<<<Mrows, 256, 0, stream>>>(Y, O, dec_ln2s + l * Dm, dec_ln2b + l * Dm, Ybf);

        // feed-forward
        gemm_bf<64,128,true,true,true><<<dim3(16, 32, 1), 256, 0, stream>>>(
            Ybf, dw1_t + (size_t)l * DFFm * Dm, FHbf, dec_b1 + l * DFFm,
            Dm, Dm, Dm, DFFm, 0,0,0,0,0,0, 1);
        gemm_bf<64,64,false,true,false><<<dim3(8, 32, 1), 256, 0, stream>>>(
            FHbf, dw2_t + (size_t)l * Dm * DFFm, O, dec_b2 + l * Dm,
            DFFm, DFFm, DFFm, Dm, 0,0,0,0,0,0, 1);
        add_ln<<<Mrows, 256, 0, stream>>>(Y, O, dec_ln3s + l * Dm, dec_ln3b + l * Dm, Ybf);
    }

    // final projection to vocab
    gemm_bf<128,128,false,true,false><<<dim3(Vm / 128, 16, 1), 256, 0, stream>>>(
        Ybf, fcw_t, (float*)d_out, fc_b,
        Dm, Dm, Dm, Vm, 0,0,0,0,0,0, 1);
}

// Round 5
// 1821.154 us; speedup vs baseline: 4.1712x; 1.0646x over previous
//
#include <hip/hip_runtime.h>
#include <cmath>

#define Dm   512
#define Hn   8
#define Ln   6
#define DFFm 2048
#define Vm   32000
#define Bn   2
#define Sn   1024
#define DHm  64
#define Mrows (Bn*Sn)   // 2048

typedef unsigned short ushort_t;
typedef __attribute__((ext_vector_type(8))) short          s16x8;
typedef __attribute__((ext_vector_type(8))) unsigned short u16x8;
typedef __attribute__((ext_vector_type(4))) float          f32x4;

__device__ __forceinline__ ushort_t f2bf(float x) {
    union { float f; unsigned u; } un; un.f = x;
    unsigned r = un.u + 0x7fffu + ((un.u >> 16) & 1u);
    return (ushort_t)(r >> 16);
}

// ---------------------------------------------------------------------------
// Stage TR rows x 64 k of bf16 from global (row-major, ld elements) into LDS
// tile (row stride 64 ushorts = 128B, 8 slots of 16B per row).
// LDS(r, sl) holds global slot (sl ^ (r&7))  [T2 swizzle via pre-swizzled
// source; global_load_lds writes linearly: lane i -> row i>>3, slot i&7].
// ---------------------------------------------------------------------------
template<int TR>
__device__ __forceinline__ void stage_tile(const ushort_t* __restrict__ src, int ld,
                                           ushort_t* lds, int k0, int w, int lane)
{
    #pragma unroll
    for (int c = 0; c < TR / 32; ++c) {
        const int rb = (w * (TR / 32) + c) * 8;           // wave-uniform row base
        const int r  = rb + (lane >> 3);
        const ushort_t* gp = src + (size_t)r * ld + k0
                           + (((lane & 7) ^ ((lane >> 3) & 7)) << 3);
        __builtin_amdgcn_global_load_lds(
            (const __attribute__((address_space(1))) void*)gp,
            (__attribute__((address_space(3))) void*)(lds + rb * 64),
            16, 0, 0);
    }
}

// read 8 bf16: LDS tile row r, logical 16B-slot st (0..7)
__device__ __forceinline__ s16x8 ldrd(const ushort_t* lds, int r, int st)
{
    return *(const s16x8*)&lds[r * 64 + ((st ^ (r & 7)) << 3)];
}

// ---------------------------------------------------------------------------
// bf16 MFMA GEMM: C[M,N] = A[M,K] @ Bt[N,K]^T  (+bias) (+relu)
// Double-buffered LDS: prefetch tile t+1 issued before computing tile t,
// single barrier per K-step (loads fly under the MFMA of the current tile).
// VTOUT: columns >= voff are written transposed to VTp[z][d][s] (z from row/h)
// instead of row-major C — fuses the V-transpose into the QKV/KV projections.
// ---------------------------------------------------------------------------
template<int TM, int TN, bool OBF, bool BIAS, bool RELU, bool VTOUT>
__global__ __launch_bounds__(256) void gemm_bf(
    const ushort_t* __restrict__ A, const ushort_t* __restrict__ Bt,
    void* __restrict__ Cv, const float* __restrict__ bias,
    int K, int lda, int ldb, int ldc,
    long A_sb, long A_sh, long B_sb, long B_sh, long C_sb, long C_sh, int nh,
    ushort_t* __restrict__ VTp, int voff)
{
    constexpr int FI = TM / 32, FJ = TN / 32;   // 16x16 frags per wave
    __shared__ __align__(16) ushort_t As[2][TM * 64];
    __shared__ __align__(16) ushort_t Bs[2][TN * 64];

    const int z = blockIdx.z, b = z / nh, h = z - b * nh;
    A  += (size_t)b * A_sb + (size_t)h * A_sh;
    Bt += (size_t)b * B_sb + (size_t)h * B_sh;

    const int tid  = threadIdx.x;
    const int w    = tid >> 6, lane = tid & 63;
    const int m0   = blockIdx.y * TM, n0 = blockIdx.x * TN;
    const int rw   = (w >> 1) * (TM / 2);       // wave sub-tile row base
    const int cn   = (w & 1) * (TN / 2);        // wave sub-tile col base
    const int l15  = lane & 15, l4 = lane >> 4;

    const ushort_t* Ab = A + (size_t)m0 * lda;
    const ushort_t* Bb = Bt + (size_t)n0 * ldb;

    f32x4 acc[FI][FJ] = {};

    stage_tile<TM>(Ab, lda, As[0], 0, w, lane);
    stage_tile<TN>(Bb, ldb, Bs[0], 0, w, lane);
    __syncthreads();

    const int nk = K >> 6;
    for (int t = 0; t < nk; ++t) {
        const int cur = t & 1;
        if (t + 1 < nk) {
            stage_tile<TM>(Ab, lda, As[cur ^ 1], (t + 1) << 6, w, lane);
            stage_tile<TN>(Bb, ldb, Bs[cur ^ 1], (t + 1) << 6, w, lane);
        }
        #pragma unroll
        for (int ks = 0; ks < 2; ++ks) {
            const int st = ks * 4 + l4;
            s16x8 av[FI], bv[FJ];
            #pragma unroll
            for (int i = 0; i < FI; ++i) av[i] = ldrd(As[cur], rw + i * 16 + l15, st);
            #pragma unroll
            for (int j = 0; j < FJ; ++j) bv[j] = ldrd(Bs[cur], cn + j * 16 + l15, st);
            #pragma unroll
            for (int i = 0; i < FI; ++i)
                #pragma unroll
                for (int j = 0; j < FJ; ++j)
                    acc[i][j] = __builtin_amdgcn_mfma_f32_16x16x32_bf16(
                                    av[i], bv[j], acc[i][j], 0, 0, 0);
        }
        __syncthreads();
    }

    // epilogue: D[col=lane&15, row=(lane>>4)*4 + r]  (m89-verified layout)
    const int colb = n0 + cn + l15;
    const int rowb = m0 + rw + (l4 << 2);
    float bvv[FJ];
    #pragma unroll
    for (int j = 0; j < FJ; ++j) bvv[j] = BIAS ? bias[colb + j * 16] : 0.f;

    if constexpr (OBF) {
        ushort_t* C = (ushort_t*)Cv + (size_t)b * C_sb + (size_t)h * C_sh;
        #pragma unroll
        for (int i = 0; i < FI; ++i)
            #pragma unroll
            for (int r = 0; r < 4; ++r) {
                const int row = rowb + i * 16 + r;
                #pragma unroll
                for (int j = 0; j < FJ; ++j) {
                    float v = acc[i][j][r] + bvv[j];
                    if (RELU) v = fmaxf(v, 0.f);
                    const int col = colb + j * 16;
                    if (VTOUT && col >= voff) {
                        const int hc = (col - voff) >> 6, d = (col - voff) & 63;
                        const int zz = (row >> 10) * 8 + hc;
                        VTp[(size_t)zz * (64 * Sn) + (size_t)d * Sn + (row & (Sn - 1))] = f2bf(v);
                    } else {
                        C[(size_t)row * ldc + col] = f2bf(v);
                    }
                }
            }
    } else {
        float* C = (float*)Cv + (size_t)b * C_sb + (size_t)h * C_sh;
        #pragma unroll
        for (int i = 0; i < FI; ++i)
            #pragma unroll
            for (int r = 0; r < 4; ++r) {
                const size_t row = rowb + i * 16 + r;
                #pragma unroll
                for (int j = 0; j < FJ; ++j) {
                    float v = acc[i][j][r] + bvv[j];
                    if (RELU) v = fmaxf(v, 0.f);
                    C[row * ldc + colb + j * 16] = v;
                }
            }
    }
}

// ---------------------------------------------------------------------------
// Flash-fused attention. One block = 4 waves = 64 q-rows of one (b,h).
// Q from Qp (row-major, ldq, head offset h*64); K from Kp (ldk likewise);
// V^T from VTp[z][d][s] (ld = Sn). Output AO[b*Sn+q][h*64+d] bf16.
// MODE 0: pad mask (tok[k]==0 blocked); MODE 1: causal.
// ---------------------------------------------------------------------------
template<int MODE>
__global__ __launch_bounds__(256) void flash_attn(
    const ushort_t* __restrict__ Qp, const ushort_t* __restrict__ Kp,
    const ushort_t* __restrict__ VTp, ushort_t* __restrict__ AO,
    const int* __restrict__ tok, int ldq, int ldk)
{
    __shared__ __align__(16) ushort_t Ks[2][64 * 64];
    __shared__ __align__(16) ushort_t Vs[2][64 * 64];
    __shared__ __align__(16) ushort_t Ps[4][16 * 64];
    __shared__ float msk[Sn];

    const int z = blockIdx.y, b = z >> 3, h = z & 7;
    const int qb = blockIdx.x * 64;
    const int tid = threadIdx.x, w = tid >> 6, lane = tid & 63;
    const int l15 = lane & 15, l4 = lane >> 4;

    const ushort_t* Qbase = Qp + (size_t)b * Sn * ldq + h * 64;
    const ushort_t* Kbase = Kp + (size_t)b * Sn * ldk + h * 64;
    const ushort_t* Vbase = VTp + (size_t)z * 64 * Sn;
    ushort_t* Obase = AO + ((size_t)(b * Sn + qb)) * Dm + h * 64;

    if (MODE == 0) {
        const int* tb = tok + (size_t)b * Sn;
        for (int i = tid; i < Sn; i += 256) msk[i] = (tb[i] == 0) ? 1.f : 0.f;
    }

    // Q fragments in registers (A-operand layout)
    const int qrow = qb + w * 16 + l15;
    s16x8 qv[2];
    qv[0] = *(const s16x8*)(Qbase + (size_t)qrow * ldq + l4 * 8);
    qv[1] = *(const s16x8*)(Qbase + (size_t)qrow * ldq + 32 + l4 * 8);

    f32x4 o[4] = {};
    float m[4], lsum[4];
    #pragma unroll
    for (int r = 0; r < 4; ++r) { m[r] = -1e30f; lsum[r] = 0.f; }

    const int nt = (MODE == 1) ? (qb / 64 + 1) : (Sn / 64);

    stage_tile<64>(Kbase, ldk, Ks[0], 0, w, lane);
    stage_tile<64>(Vbase, Sn, Vs[0], 0, w, lane);
    __syncthreads();

    for (int kt = 0; kt < nt; ++kt) {
        const int cur = kt & 1;
        if (kt + 1 < nt) {
            stage_tile<64>(Kbase + (size_t)((kt + 1) * 64) * ldk, ldk, Ks[cur ^ 1], 0, w, lane);
            stage_tile<64>(Vbase, Sn, Vs[cur ^ 1], (kt + 1) * 64, w, lane);
        }

        // S = Q @ K^T
        f32x4 s[4] = {};
        #pragma unroll
        for (int ks = 0; ks < 2; ++ks) {
            const int st = ks * 4 + l4;
            #pragma unroll
            for (int j = 0; j < 4; ++j) {
                s16x8 bv = ldrd(Ks[cur], j * 16 + l15, st);
                s[j] = __builtin_amdgcn_mfma_f32_16x16x32_bf16(qv[ks], bv, s[j], 0, 0, 0);
            }
        }

        // scale + mask
        #pragma unroll
        for (int j = 0; j < 4; ++j) {
            const int col = kt * 64 + j * 16 + l15;
            #pragma unroll
            for (int r = 0; r < 4; ++r) {
                float v = s[j][r] * 0.125f;
                if (MODE == 0) { if (msk[col] != 0.f) v = -1e9f; }
                else           { if (col > qb + w * 16 + l4 * 4 + r) v = -1e9f; }
                s[j][r] = v;
            }
        }

        // row max over the 64 tile cols (4 frags x 16 lanes)
        float mt[4];
        #pragma unroll
        for (int r = 0; r < 4; ++r)
            mt[r] = fmaxf(fmaxf(s[0][r], s[1][r]), fmaxf(s[2][r], s[3][r]));
        #pragma unroll
        for (int mk = 1; mk < 16; mk <<= 1)
            #pragma unroll
            for (int r = 0; r < 4; ++r)
                mt[r] = fmaxf(mt[r], __shfl_xor(mt[r], mk));

        float al[4];
        #pragma unroll
        for (int r = 0; r < 4; ++r) {
            const float mn = fmaxf(m[r], mt[r]);
            al[r] = __expf(m[r] - mn);
            m[r] = mn;
        }

        // P = exp(S - m); write bf16 into per-wave swizzled LDS tile
        float rs[4] = {0.f, 0.f, 0.f, 0.f};
        ushort_t* pw = Ps[w];
        #pragma unroll
        for (int j = 0; j < 4; ++j) {
            const int slot = j * 2 + (l15 >> 3), e = l15 & 7;
            #pragma unroll
            for (int r = 0; r < 4; ++r) {
                const float pvv = __expf(s[j][r] - m[r]);
                rs[r] += pvv;
                const int row = l4 * 4 + r;
                pw[row * 64 + ((slot ^ (row & 7)) << 3) + e] = f2bf(pvv);
            }
        }
        #pragma unroll
        for (int mk = 1; mk < 16; mk <<= 1)
            #pragma unroll
            for (int r = 0; r < 4; ++r)
                rs[r] += __shfl_xor(rs[r], mk);
        #pragma unroll
        for (int r = 0; r < 4; ++r) lsum[r] = lsum[r] * al[r] + rs[r];

        // rescale O, then O += P @ V
        #pragma unroll
        for (int jd = 0; jd < 4; ++jd)
            #pragma unroll
            for (int r = 0; r < 4; ++r)
                o[jd][r] *= al[r];
        #pragma unroll
        for (int ks2 = 0; ks2 < 2; ++ks2) {
            const int st2 = ks2 * 4 + l4;
            s16x8 pa = ldrd(pw, l15, st2);
            #pragma unroll
            for (int jd = 0; jd < 4; ++jd) {
                s16x8 bv2 = ldrd(Vs[cur], jd * 16 + l15, st2);
                o[jd] = __builtin_amdgcn_mfma_f32_16x16x32_bf16(pa, bv2, o[jd], 0, 0, 0);
            }
        }
        __syncthreads();
    }

    // epilogue: O /= l, write bf16
    #pragma unroll
    for (int r = 0; r < 4; ++r) lsum[r] = 1.f / lsum[r];
    #pragma unroll
    for (int jd = 0; jd < 4; ++jd)
        #pragma unroll
        for (int r = 0; r < 4; ++r)
            Obase[(size_t)(w * 16 + l4 * 4 + r) * Dm + jd * 16 + l15] =
                f2bf(o[jd][r] * lsum[r]);
}

// ---------------------------------------------------------------------------
// Merged weight transpose+cvt: all 12 weight groups in one dispatch.
// Each 32x32 tile block finds its descriptor by prefix-sum scan.
// in fp32 [l][R][C] -> out bf16 [l][C][R].
// ---------------------------------------------------------------------------
struct WEnt { const float* src; ushort_t* dst; int R, C, tile0; };
struct WPack { WEnt e[12]; };

__global__ __launch_bounds__(256) void wcvt_all(WPack p)
{
    const int bid = blockIdx.x;
    int i = 0;
    #pragma unroll
    for (int k = 1; k < 12; ++k) if (bid >= p.e[k].tile0) i = k;
    const WEnt wd = p.e[i];
    const int rel = bid - wd.tile0;
    const int tC = wd.C >> 5, tR = wd.R >> 5;
    const int tpl = tC * tR;
    const int l = rel / tpl, t2 = rel - l * tpl;
    const int ty = t2 / tC, tx = t2 - ty * tC;

    const float* in  = wd.src + (size_t)l * wd.R * wd.C;
    ushort_t*    out = wd.dst + (size_t)l * wd.R * wd.C;

    __shared__ float tbuf[32][33];
    const int r0 = ty * 32, c0 = tx * 32;
    const int tid = threadIdx.x;
    const int r = tid >> 5, c = tid & 31;
    #pragma unroll
    for (int q = 0; q < 4; ++q)
        tbuf[r + q * 8][c] = in[(size_t)(r0 + r + q * 8) * wd.C + c0 + c];
    __syncthreads();
    const int c2 = tid >> 5, r2 = tid & 31;
    #pragma unroll
    for (int q = 0; q < 4; ++q)
        out[(size_t)(c0 + c2 + q * 8) * wd.R + r0 + r2] = f2bf(tbuf[r2][c2 + q * 8]);
}

// ---------------------------------------------------------------------------
// x = layernorm(x + o)*s + b (fp32, in-place) and bf16 copy xbf.
// ---------------------------------------------------------------------------
__global__ __launch_bounds__(256) void add_ln(
    float* __restrict__ x, const float* __restrict__ o,
    const float* __restrict__ s, const float* __restrict__ bb,
    ushort_t* __restrict__ xbf)
{
    const long row = blockIdx.x;
    const int t = threadIdx.x;
    float* xr = x + row * Dm;
    const float* orr = o + row * Dm;
    float v0 = xr[t] + orr[t];
    float v1 = xr[t + 256] + orr[t + 256];

    float sum = v0 + v1, ssq = v0 * v0 + v1 * v1;
    __shared__ float red[8];
    for (int off = 32; off; off >>= 1) {
        sum += __shfl_down(sum, off);
        ssq += __shfl_down(ssq, off);
    }
    const int lane = t & 63, w = t >> 6;
    if (lane == 0) { red[w] = sum; red[4 + w] = ssq; }
    __syncthreads();
    sum = red[0] + red[1] + red[2] + red[3];
    ssq = red[4] + red[5] + red[6] + red[7];

    const float mean = sum * (1.f / Dm);
    const float var  = ssq * (1.f / Dm) - mean * mean;
    const float r = rsqrtf(var + 1e-5f);
    const float r0 = (v0 - mean) * r * s[t] + bb[t];
    const float r1 = (v1 - mean) * r * s[t + 256] + bb[t + 256];
    xr[t] = r0; xr[t + 256] = r1;
    xbf[row * Dm + t] = f2bf(r0);
    xbf[row * Dm + t + 256] = f2bf(r1);
}

// ---------------------------------------------------------------------------
// Embeddings for both streams in one dispatch: grid.y 0 -> src, 1 -> trg.
// ---------------------------------------------------------------------------
__global__ __launch_bounds__(256) void embed_pe(
    const int* __restrict__ tokA, const float* __restrict__ embA,
    float* __restrict__ outA, ushort_t* __restrict__ outbfA,
    const int* __restrict__ tokB, const float* __restrict__ embB,
    float* __restrict__ outB, ushort_t* __restrict__ outbfB)
{
    const int bs = blockIdx.x;
    const int s = bs % Sn;
    const int t = threadIdx.x;
    const int*      tok   = blockIdx.y ? tokB : tokA;
    const float*    emb   = blockIdx.y ? embB : embA;
    float*          out   = blockIdx.y ? outB : outA;
    ushort_t*       outbf = blockIdx.y ? outbfB : outbfA;
    const int token = tok[bs];
    #pragma unroll
    for (int r = 0; r < 2; ++r) {
        const int d = t + r * 256;
        const int i = d & ~1;
        const float ang = (float)s * powf(10000.0f, -(float)i / (float)Dm);
        const float pe = (d & 1) ? cosf(ang) : sinf(ang);
        const float v = emb[(size_t)token * Dm + d] * 22.627416997969522f + pe;
        out[(size_t)bs * Dm + d] = v;
        outbf[(size_t)bs * Dm + d] = f2bf(v);
    }
}

// ---------------------------------------------------------------------------
extern "C" void kernel_launch(void* const* d_in, const int* in_sizes, int n_in,
                              void* d_out, int out_size, void* d_ws, size_t ws_size,
                              hipStream_t stream)
{
    const int*   batch_src = (const int*)d_in[0];
    const int*   trg       = (const int*)d_in[1];
    const float* src_emb   = (const float*)d_in[2];
    const float* trg_emb   = (const float*)d_in[3];
    const float* fc_w      = (const float*)d_in[4];
    const float* fc_b      = (const float*)d_in[5];
    const float* enc_wqkv  = (const float*)d_in[6];
    const float* enc_wo    = (const float*)d_in[7];
    const float* enc_ln1s  = (const float*)d_in[8];
    const float* enc_ln1b  = (const float*)d_in[9];
    const float* enc_w1    = (const float*)d_in[10];
    const float* enc_b1    = (const float*)d_in[11];
    const float* enc_w2    = (const float*)d_in[12];
    const float* enc_b2    = (const float*)d_in[13];
    const float* enc_ln2s  = (const float*)d_in[14];
    const float* enc_ln2b  = (const float*)d_in[15];
    const float* dec_wqkv  = (const float*)d_in[16];
    const float* dec_wo    = (const float*)d_in[17];
    const float* dec_ln1s  = (const float*)d_in[18];
    const float* dec_ln1b  = (const float*)d_in[19];
    const float* dec_wq    = (const float*)d_in[20];
    const float* dec_wkv   = (const float*)d_in[21];
    const float* dec_woc   = (const float*)d_in[22];
    const float* dec_ln2s  = (const float*)d_in[23];
    const float* dec_ln2b  = (const float*)d_in[24];
    const float* dec_w1    = (const float*)d_in[25];
    const float* dec_b1    = (const float*)d_in[26];
    const float* dec_w2    = (const float*)d_in[27];
    const float* dec_b2    = (const float*)d_in[28];
    const float* dec_ln3s  = (const float*)d_in[29];
    const float* dec_ln3b  = (const float*)d_in[30];
    (void)in_sizes; (void)n_in; (void)out_size; (void)ws_size;

    char* p = (char*)d_ws;
    auto alloc = [&](size_t bytes) { char* r = p; p += (bytes + 255) & ~(size_t)255; return r; };
    float*    X     = (float*)alloc((size_t)Mrows * Dm * 4);
    float*    Y     = (float*)alloc((size_t)Mrows * Dm * 4);
    float*    O     = (float*)alloc((size_t)Mrows * Dm * 4);
    ushort_t* Xbf   = (ushort_t*)alloc((size_t)Mrows * Dm * 2);
    ushort_t* Ybf   = (ushort_t*)alloc((size_t)Mrows * Dm * 2);
    ushort_t* QKVbf = (ushort_t*)alloc((size_t)Mrows * 3 * Dm * 2);
    ushort_t* AObf  = (ushort_t*)alloc((size_t)Mrows * Dm * 2);
    ushort_t* FHbf  = (ushort_t*)alloc((size_t)Mrows * DFFm * 2);
    ushort_t* QCbf  = (ushort_t*)alloc((size_t)Mrows * Dm * 2);
    ushort_t* KVbf  = (ushort_t*)alloc((size_t)Mrows * 2 * Dm * 2);
    ushort_t* VT    = (ushort_t*)alloc((size_t)16 * DHm * Sn * 2);
    ushort_t* ewqkv_t = (ushort_t*)alloc((size_t)Ln * 3 * Dm * Dm * 2);
    ushort_t* ewo_t   = (ushort_t*)alloc((size_t)Ln * Dm * Dm * 2);
    ushort_t* ew1_t   = (ushort_t*)alloc((size_t)Ln * DFFm * Dm * 2);
    ushort_t* ew2_t   = (ushort_t*)alloc((size_t)Ln * Dm * DFFm * 2);
    ushort_t* dwqkv_t = (ushort_t*)alloc((size_t)Ln * 3 * Dm * Dm * 2);
    ushort_t* dwo_t   = (ushort_t*)alloc((size_t)Ln * Dm * Dm * 2);
    ushort_t* dwq_t   = (ushort_t*)alloc((size_t)Ln * Dm * Dm * 2);
    ushort_t* dwkv_t  = (ushort_t*)alloc((size_t)Ln * 2 * Dm * Dm * 2);
    ushort_t* dwoc_t  = (ushort_t*)alloc((size_t)Ln * Dm * Dm * 2);
    ushort_t* dw1_t   = (ushort_t*)alloc((size_t)Ln * DFFm * Dm * 2);
    ushort_t* dw2_t   = (ushort_t*)alloc((size_t)Ln * Dm * DFFm * 2);
    ushort_t* fcw_t   = (ushort_t*)alloc((size_t)Vm * Dm * 2);

    // ---------------- merged weight transpose+cvt (one dispatch) ----------
    {
        WPack pk;
        auto set = [&](int i, const float* s, ushort_t* d, int R, int C, int nl, int& acc) {
            pk.e[i] = { s, d, R, C, acc };
            acc += (R >> 5) * (C >> 5) * nl;
        };
        int acc = 0;
        set(0,  enc_wqkv, ewqkv_t, Dm,   3 * Dm, Ln, acc);
        set(1,  enc_wo,   ewo_t,   Dm,   Dm,     Ln, acc);
        set(2,  enc_w1,   ew1_t,   Dm,   DFFm,   Ln, acc);
        set(3,  enc_w2,   ew2_t,   DFFm, Dm,     Ln, acc);
        set(4,  dec_wqkv, dwqkv_t, Dm,   3 * Dm, Ln, acc);
        set(5,  dec_wo,   dwo_t,   Dm,   Dm,     Ln, acc);
        set(6,  dec_wq,   dwq_t,   Dm,   Dm,     Ln, acc);
        set(7,  dec_wkv,  dwkv_t,  Dm,   2 * Dm, Ln, acc);
        set(8,  dec_woc,  dwoc_t,  Dm,   Dm,     Ln, acc);
        set(9,  dec_w1,   dw1_t,   Dm,   DFFm,   Ln, acc);
        set(10, dec_w2,   dw2_t,   DFFm, Dm,     Ln, acc);
        set(11, fc_w,     fcw_t,   Dm,   Vm,     1,  acc);
        wcvt_all<<<acc, 256, 0, stream>>>(pk);
    }

    embed_pe<<<dim3(Mrows, 2), 256, 0, stream>>>(
        batch_src, src_emb, X, Xbf, trg, trg_emb, Y, Ybf);

    // --------------------------------- encoder ----------------------------
    for (int l = 0; l < Ln; ++l) {
        gemm_bf<64,128,true,false,false,true><<<dim3(12, 32, 1), 256, 0, stream>>>(
            Xbf, ewqkv_t + (size_t)l * 3 * Dm * Dm, QKVbf, nullptr,
            Dm, Dm, Dm, 3 * Dm, 0,0,0,0,0,0, 1, VT, 2 * Dm);
        flash_attn<0><<<dim3(16, 16), 256, 0, stream>>>(
            QKVbf, QKVbf + Dm, VT, AObf, batch_src, 3 * Dm, 3 * Dm);
        gemm_bf<64,64,false,false,false,false><<<dim3(8, 32, 1), 256, 0, stream>>>(
            AObf, ewo_t + (size_t)l * Dm * Dm, O, nullptr,
            Dm, Dm, Dm, Dm, 0,0,0,0,0,0, 1, nullptr, 0);
        add_ln<<<Mrows, 256, 0, stream>>>(X, O, enc_ln1s + l * Dm, enc_ln1b + l * Dm, Xbf);
        gemm_bf<64,128,true,true,true,false><<<dim3(16, 32, 1), 256, 0, stream>>>(
            Xbf, ew1_t + (size_t)l * DFFm * Dm, FHbf, enc_b1 + l * DFFm,
            Dm, Dm, Dm, DFFm, 0,0,0,0,0,0, 1, nullptr, 0);
        gemm_bf<64,64,false,true,false,false><<<dim3(8, 32, 1), 256, 0, stream>>>(
            FHbf, ew2_t + (size_t)l * Dm * DFFm, O, enc_b2 + l * Dm,
            DFFm, DFFm, DFFm, Dm, 0,0,0,0,0,0, 1, nullptr, 0);
        add_ln<<<Mrows, 256, 0, stream>>>(X, O, enc_ln2s + l * Dm, enc_ln2b + l * Dm, Xbf);
    }

    // --------------------------------- decoder ----------------------------
    for (int l = 0; l < Ln; ++l) {
        // self-attention (causal)
        gemm_bf<64,128,true,false,false,true><<<dim3(12, 32, 1), 256, 0, stream>>>(
            Ybf, dwqkv_t + (size_t)l * 3 * Dm * Dm, QKVbf, nullptr,
            Dm, Dm, Dm, 3 * Dm, 0,0,0,0,0,0, 1, VT, 2 * Dm);
        flash_attn<1><<<dim3(16, 16), 256, 0, stream>>>(
            QKVbf, QKVbf + Dm, VT, AObf, nullptr, 3 * Dm, 3 * Dm);
        gemm_bf<64,64,false,false,false,false><<<dim3(8, 32, 1), 256, 0, stream>>>(
            AObf, dwo_t + (size_t)l * Dm * Dm, O, nullptr,
            Dm, Dm, Dm, Dm, 0,0,0,0,0,0, 1, nullptr, 0);
        add_ln<<<Mrows, 256, 0, stream>>>(Y, O, dec_ln1s + l * Dm, dec_ln1b + l * Dm, Ybf);

        // cross-attention (pad mask)
        gemm_bf<64,64,true,false,false,false><<<dim3(8, 32, 1), 256, 0, stream>>>(
            Ybf, dwq_t + (size_t)l * Dm * Dm, QCbf, nullptr,
            Dm, Dm, Dm, Dm, 0,0,0,0,0,0, 1, nullptr, 0);
        gemm_bf<64,128,true,false,false,true><<<dim3(8, 32, 1), 256, 0, stream>>>(
            Xbf, dwkv_t + (size_t)l * 2 * Dm * Dm, KVbf, nullptr,
            Dm, Dm, Dm, 2 * Dm, 0,0,0,0,0,0, 1, VT, Dm);
        flash_attn<0><<<dim3(16, 16), 256, 0, stream>>>(
            QCbf, KVbf, VT, AObf, batch_src, Dm, 2 * Dm);
        gemm_bf<64,64,false,false,false,false><<<dim3(8, 32, 1), 256, 0, stream>>>(
            AObf, dwoc_t + (size_t)l * Dm * Dm, O, nullptr,
            Dm, Dm, Dm, Dm, 0,0,0,0,0,0, 1, nullptr, 0);
        add_ln<<<Mrows, 256, 0, stream>>>(Y, O, dec_ln2s + l * Dm, dec_ln2b + l * Dm, Ybf);

        // feed-forward
        gemm_bf<64,128,true,true,true,false><<<dim3(16, 32, 1), 256, 0, stream>>>(
            Ybf, dw1_t + (size_t)l * DFFm * Dm, FHbf, dec_b1 + l * DFFm,
            Dm, Dm, Dm, DFFm, 0,0,0,0,0,0, 1, nullptr, 0);
        gemm_bf<64,64,false,true,false,false><<<dim3(8, 32, 1), 256, 0, stream>>>(
            FHbf, dw2_t + (size_t)l * Dm * DFFm, O, dec_b2 + l * Dm,
            DFFm, DFFm, DFFm, Dm, 0,0,0,0,0,0, 1, nullptr, 0);
        add_ln<<<Mrows, 256, 0, stream>>>(Y, O, dec_ln3s + l * Dm, dec_ln3b + l * Dm, Ybf);
    }

    // final projection to vocab
    gemm_bf<128,128,false,true,false,false><<<dim3(Vm / 128, 16, 1), 256, 0, stream>>>(
        Ybf, fcw_t, (float*)d_out, fc_b,
        Dm, Dm, Dm, Vm, 0,0,0,0,0,0, 1, nullptr, 0);
}